// Round 2
// baseline (379.806 us; speedup 1.0000x reference)
//
#include <hip/hip_runtime.h>
#include <hip/hip_bf16.h>

typedef __attribute__((ext_vector_type(8))) short short8;
typedef __attribute__((ext_vector_type(4))) float f32x4;

#define B_ 8
#define T_ 1024
#define D_ 1024
#define H_ 16
#define G_ 4
#define HD_ 64
#define QKVW 1536   // H*HD + 2*G*HD = 1024 + 512

// ---------------------------------------------------------------------------
// fp32 -> bf16 conversion, 8 elems/thread, vectorized. n must be /8.
// ---------------------------------------------------------------------------
__global__ __launch_bounds__(256) void cvt_f32_bf16(
    const float* __restrict__ in, __hip_bfloat16* __restrict__ out, int n)
{
    int i = (blockIdx.x * 256 + threadIdx.x) * 8;
    if (i >= n) return;
    float4 a = *reinterpret_cast<const float4*>(in + i);
    float4 b = *reinterpret_cast<const float4*>(in + i + 4);
    union { short8 s; __hip_bfloat16 h[8]; } u;
    u.h[0] = __float2bfloat16(a.x); u.h[1] = __float2bfloat16(a.y);
    u.h[2] = __float2bfloat16(a.z); u.h[3] = __float2bfloat16(a.w);
    u.h[4] = __float2bfloat16(b.x); u.h[5] = __float2bfloat16(b.y);
    u.h[6] = __float2bfloat16(b.z); u.h[7] = __float2bfloat16(b.w);
    *reinterpret_cast<short8*>(out + i) = u.s;
}

// ---------------------------------------------------------------------------
// Generic bf16 GEMM: C[M][N] = A[M][K] * B[K][N], A,B row-major bf16, fp32 acc.
// Output type templated (bf16 intermediate / fp32 final).
// Block: 256 threads (4 waves), tile 64x64, BK=32.
// ---------------------------------------------------------------------------
template <typename CT>
__global__ __launch_bounds__(256) void gemm_bf16(
    const __hip_bfloat16* __restrict__ A,
    const __hip_bfloat16* __restrict__ B,
    CT* __restrict__ C,
    int M, int N, int K)
{
    __shared__ __hip_bfloat16 As[64][48];
    __shared__ __hip_bfloat16 Bt[64][48];   // B transposed: Bt[n][k]

    const int tid  = threadIdx.x;
    const int lane = tid & 63;
    const int wid  = tid >> 6;
    const int m0 = blockIdx.y * 64;
    const int n0 = blockIdx.x * 64;

    f32x4 acc[4] = {f32x4{0,0,0,0}, f32x4{0,0,0,0}, f32x4{0,0,0,0}, f32x4{0,0,0,0}};

    const int arow = wid * 16 + (lane & 15);
    const int kf   = (lane >> 4) * 8;

    for (int kk = 0; kk < K; kk += 32) {
        {
            int r = tid >> 2, c = (tid & 3) * 8;
            *reinterpret_cast<short8*>(&As[r][c]) =
                *reinterpret_cast<const short8*>(A + (size_t)(m0 + r) * K + kk + c);
        }
        #pragma unroll
        for (int p = 0; p < 8; ++p) {
            int kr = (tid >> 6) + p * 4;
            int n  = tid & 63;
            Bt[n][kr] = B[(size_t)(kk + kr) * N + n0 + n];
        }
        __syncthreads();

        short8 afrag = *reinterpret_cast<const short8*>(&As[arow][kf]);
        #pragma unroll
        for (int nf = 0; nf < 4; ++nf) {
            short8 bfrag = *reinterpret_cast<const short8*>(&Bt[(lane & 15) + 16 * nf][kf]);
            acc[nf] = __builtin_amdgcn_mfma_f32_16x16x32_bf16(afrag, bfrag, acc[nf], 0, 0, 0);
        }
        __syncthreads();
    }

    const int rowb = m0 + wid * 16 + (lane >> 4) * 4;
    const int colb = n0 + (lane & 15);
    #pragma unroll
    for (int nf = 0; nf < 4; ++nf)
        #pragma unroll
        for (int r = 0; r < 4; ++r) {
            float v = acc[nf][r];
            if constexpr (__is_same(CT, float))
                C[(size_t)(rowb + r) * N + colb + 16 * nf] = v;
            else
                C[(size_t)(rowb + r) * N + colb + 16 * nf] = __float2bfloat16(v);
        }
}

// ---------------------------------------------------------------------------
// L2-normalize q and k head vectors in-place inside the qkv buffer.
// ---------------------------------------------------------------------------
__global__ __launch_bounds__(256) void l2norm_qk(__hip_bfloat16* __restrict__ qkv)
{
    const int lane = threadIdx.x & 63;
    const int wid  = threadIdx.x >> 6;
    const int vec  = blockIdx.x * 4 + wid;

    size_t base;
    if (vec < B_ * T_ * H_) {                       // q vector
        int bt = vec >> 4, h = vec & 15;
        base = (size_t)bt * QKVW + h * HD_;
    } else {                                        // k vector
        int v = vec - B_ * T_ * H_;
        int bt = v >> 2, g = v & 3;
        base = (size_t)bt * QKVW + H_ * HD_ + g * HD_;
    }

    float val = __bfloat162float(qkv[base + lane]);
    float s = val * val;
    #pragma unroll
    for (int off = 32; off; off >>= 1) s += __shfl_xor(s, off, 64);
    float scale = 1.0f / (sqrtf(s) + 1e-10f);
    qkv[base + lane] = __float2bfloat16(val * scale);
}

// ---------------------------------------------------------------------------
// Flash attention, causal, GQA. Block = 4 waves, handles (b, h, 64 q-rows).
// ---------------------------------------------------------------------------
__global__ __launch_bounds__(256) void attn_fwd(
    const __hip_bfloat16* __restrict__ qkv,
    __hip_bfloat16* __restrict__ out)   // [B,T,H*HD]
{
    const int qt = blockIdx.x;
    const int h  = blockIdx.y;
    const int b  = blockIdx.z;
    const int g  = h >> 2;

    const int tid  = threadIdx.x;
    const int lane = tid & 63;
    const int wid  = tid >> 6;

    __shared__ __hip_bfloat16 Ks[64][72];
    __shared__ __hip_bfloat16 Vt[64][72];
    __shared__ __hip_bfloat16 Ps[4][16][72];

    const int q0   = qt * 64;
    const int kf   = (lane >> 4) * 8;
    const int arow = q0 + wid * 16 + (lane & 15);

    short8 qfrag[2];
    {
        const size_t qbase = ((size_t)(b * T_ + arow)) * QKVW + h * HD_;
        qfrag[0] = *reinterpret_cast<const short8*>(qkv + qbase + kf);
        qfrag[1] = *reinterpret_cast<const short8*>(qkv + qbase + 32 + kf);
    }

    float m[4], l[4];
    f32x4 o[4] = {f32x4{0,0,0,0}, f32x4{0,0,0,0}, f32x4{0,0,0,0}, f32x4{0,0,0,0}};
    #pragma unroll
    for (int r = 0; r < 4; ++r) { m[r] = -INFINITY; l[r] = 0.f; }

    const float scale = 0.125f;   // HD^-0.5
    const int rbase = q0 + wid * 16 + (lane >> 4) * 4;

    for (int kt = 0; kt <= qt; ++kt) {
        #pragma unroll
        for (int p = 0; p < 2; ++p) {
            int r = (tid >> 3) + p * 32, c = (tid & 7) * 8;
            size_t kaddr = ((size_t)(b * T_ + kt * 64 + r)) * QKVW + H_ * HD_ + g * HD_ + c;
            *reinterpret_cast<short8*>(&Ks[r][c]) =
                *reinterpret_cast<const short8*>(qkv + kaddr);
        }
        #pragma unroll
        for (int p = 0; p < 16; ++p) {
            int idx = tid + p * 256;
            int r = idx >> 6, d = idx & 63;
            Vt[d][r] = qkv[((size_t)(b * T_ + kt * 64 + r)) * QKVW
                           + H_ * HD_ + G_ * HD_ + g * HD_ + d];
        }
        __syncthreads();

        f32x4 s[4] = {f32x4{0,0,0,0}, f32x4{0,0,0,0}, f32x4{0,0,0,0}, f32x4{0,0,0,0}};
        #pragma unroll
        for (int nf = 0; nf < 4; ++nf) {
            short8 b0 = *reinterpret_cast<const short8*>(&Ks[(lane & 15) + 16 * nf][kf]);
            short8 b1 = *reinterpret_cast<const short8*>(&Ks[(lane & 15) + 16 * nf][32 + kf]);
            s[nf] = __builtin_amdgcn_mfma_f32_16x16x32_bf16(qfrag[0], b0, s[nf], 0, 0, 0);
            s[nf] = __builtin_amdgcn_mfma_f32_16x16x32_bf16(qfrag[1], b1, s[nf], 0, 0, 0);
        }

        float rowmax[4] = {-INFINITY, -INFINITY, -INFINITY, -INFINITY};
        #pragma unroll
        for (int nf = 0; nf < 4; ++nf) {
            int col = kt * 64 + (lane & 15) + 16 * nf;
            #pragma unroll
            for (int r = 0; r < 4; ++r) {
                float v = s[nf][r] * scale;
                v = (col <= rbase + r) ? v : -1e9f;
                s[nf][r] = v;
                rowmax[r] = fmaxf(rowmax[r], v);
            }
        }
        #pragma unroll
        for (int r = 0; r < 4; ++r) {
            float v = rowmax[r];
            v = fmaxf(v, __shfl_xor(v, 1, 64));
            v = fmaxf(v, __shfl_xor(v, 2, 64));
            v = fmaxf(v, __shfl_xor(v, 4, 64));
            v = fmaxf(v, __shfl_xor(v, 8, 64));
            rowmax[r] = v;
        }

        float alpha[4];
        #pragma unroll
        for (int r = 0; r < 4; ++r) {
            float mn = fmaxf(m[r], rowmax[r]);
            alpha[r] = __expf(m[r] - mn);
            m[r] = mn;
        }
        float rowsum[4] = {0.f, 0.f, 0.f, 0.f};
        #pragma unroll
        for (int nf = 0; nf < 4; ++nf) {
            #pragma unroll
            for (int r = 0; r < 4; ++r) {
                float p = __expf(s[nf][r] - m[r]);
                s[nf][r] = p;
                rowsum[r] += p;
            }
        }
        #pragma unroll
        for (int r = 0; r < 4; ++r) {
            float v = rowsum[r];
            v += __shfl_xor(v, 1, 64);
            v += __shfl_xor(v, 2, 64);
            v += __shfl_xor(v, 4, 64);
            v += __shfl_xor(v, 8, 64);
            l[r] = l[r] * alpha[r] + v;
        }

        #pragma unroll
        for (int nf = 0; nf < 4; ++nf)
            #pragma unroll
            for (int r = 0; r < 4; ++r)
                Ps[wid][(lane >> 4) * 4 + r][(lane & 15) + 16 * nf] =
                    __float2bfloat16(s[nf][r]);
        #pragma unroll
        for (int nf = 0; nf < 4; ++nf)
            #pragma unroll
            for (int r = 0; r < 4; ++r)
                o[nf][r] *= alpha[r];

        short8 pa0 = *reinterpret_cast<const short8*>(&Ps[wid][lane & 15][kf]);
        short8 pa1 = *reinterpret_cast<const short8*>(&Ps[wid][lane & 15][32 + kf]);
        #pragma unroll
        for (int nf = 0; nf < 4; ++nf) {
            short8 b0 = *reinterpret_cast<const short8*>(&Vt[(lane & 15) + 16 * nf][kf]);
            short8 b1 = *reinterpret_cast<const short8*>(&Vt[(lane & 15) + 16 * nf][32 + kf]);
            o[nf] = __builtin_amdgcn_mfma_f32_16x16x32_bf16(pa0, b0, o[nf], 0, 0, 0);
            o[nf] = __builtin_amdgcn_mfma_f32_16x16x32_bf16(pa1, b1, o[nf], 0, 0, 0);
        }
        __syncthreads();
    }

    #pragma unroll
    for (int nf = 0; nf < 4; ++nf) {
        int col = (lane & 15) + 16 * nf;
        #pragma unroll
        for (int r = 0; r < 4; ++r) {
            float v = o[nf][r] / l[r];
            out[((size_t)(b * T_ + rbase + r)) * (H_ * HD_) + h * HD_ + col] =
                __float2bfloat16(v);
        }
    }
}

extern "C" void kernel_launch(void* const* d_in, const int* in_sizes, int n_in,
                              void* d_out, int out_size, void* d_ws, size_t ws_size,
                              hipStream_t stream) {
    // Inputs are FLOAT32 (per reference); output is FLOAT32.
    const float* x_f     = (const float*)d_in[0];   // [8192,1024]
    const float* w_qkv_f = (const float*)d_in[1];   // [1024,1536]
    const float* w_o_f   = (const float*)d_in[2];   // [1024,1024]
    float* out = (float*)d_out;

    const int NX = B_ * T_ * D_;          // 8388608
    const int NWQ = D_ * QKVW;            // 1572864
    const int NWO = D_ * D_;              // 1048576

    __hip_bfloat16* xb       = (__hip_bfloat16*)d_ws;
    __hip_bfloat16* wqkvb    = xb + NX;
    __hip_bfloat16* wob      = wqkvb + NWQ;
    __hip_bfloat16* qkv      = wob + NWO;                          // [8192][1536]
    __hip_bfloat16* attn_out = qkv + (size_t)(B_ * T_) * QKVW;     // [8192][1024]

    dim3 blk(256);

    // 0) fp32 -> bf16 conversions
    cvt_f32_bf16<<<dim3(NX / 2048), blk, 0, stream>>>(x_f, xb, NX);
    cvt_f32_bf16<<<dim3(NWQ / 2048), blk, 0, stream>>>(w_qkv_f, wqkvb, NWQ);
    cvt_f32_bf16<<<dim3(NWO / 2048), blk, 0, stream>>>(w_o_f, wob, NWO);

    // 1) qkv = x @ w_qkv   (M=8192, N=1536, K=1024)
    gemm_bf16<__hip_bfloat16><<<dim3(QKVW / 64, (B_ * T_) / 64), blk, 0, stream>>>(
        xb, wqkvb, qkv, B_ * T_, QKVW, D_);

    // 2) L2-normalize q and k head vectors in-place
    l2norm_qk<<<dim3((B_ * T_ * H_ + B_ * T_ * G_) / 4), blk, 0, stream>>>(qkv);

    // 3) flash attention -> attn_out [8192][1024] (bf16)
    attn_fwd<<<dim3(T_ / 64, H_, B_), blk, 0, stream>>>(qkv, attn_out);

    // 4) out = attn_out @ w_o   (M=8192, N=1024, K=1024) -> fp32
    gemm_bf16<float><<<dim3(D_ / 64, (B_ * T_) / 64), blk, 0, stream>>>(
        attn_out, wob, out, B_ * T_, D_, D_);
}

// Round 3
// 186.926 us; speedup vs baseline: 2.0318x; 2.0318x over previous
//
#include <hip/hip_runtime.h>
#include <hip/hip_bf16.h>

typedef __attribute__((ext_vector_type(8))) short short8;
typedef __attribute__((ext_vector_type(4))) float f32x4;

#define B_ 8
#define T_ 1024
#define D_ 1024
#define H_ 16
#define G_ 4
#define HD_ 64
#define QKVW 1536   // H*HD + 2*G*HD

#define GLOAD16(gp, lp) __builtin_amdgcn_global_load_lds( \
    (const __attribute__((address_space(1))) void*)(gp),  \
    (__attribute__((address_space(3))) void*)(lp), 16, 0, 0)

// ---------------------------------------------------------------------------
// fp32 -> bf16 conversion, 8 elems/thread.
// ---------------------------------------------------------------------------
__global__ __launch_bounds__(256) void cvt_f32_bf16(
    const float* __restrict__ in, __hip_bfloat16* __restrict__ out, int n)
{
    int i = (blockIdx.x * 256 + threadIdx.x) * 8;
    if (i >= n) return;
    float4 a = *reinterpret_cast<const float4*>(in + i);
    float4 b = *reinterpret_cast<const float4*>(in + i + 4);
    union { short8 s; __hip_bfloat16 h[8]; } u;
    u.h[0] = __float2bfloat16(a.x); u.h[1] = __float2bfloat16(a.y);
    u.h[2] = __float2bfloat16(a.z); u.h[3] = __float2bfloat16(a.w);
    u.h[4] = __float2bfloat16(b.x); u.h[5] = __float2bfloat16(b.y);
    u.h[6] = __float2bfloat16(b.z); u.h[7] = __float2bfloat16(b.w);
    *reinterpret_cast<short8*>(out + i) = u.s;
}

// ---------------------------------------------------------------------------
// fp32 [K][N] -> bf16 transposed [N][K], LDS-tiled 32x32.
// ---------------------------------------------------------------------------
__global__ __launch_bounds__(256) void cvt_transpose(
    const float* __restrict__ in, __hip_bfloat16* __restrict__ outT, int K, int N)
{
    __shared__ float tile[32][33];
    const int k0 = blockIdx.y * 32, n0 = blockIdx.x * 32;
    const int r = threadIdx.x >> 5, c = threadIdx.x & 31;
    #pragma unroll
    for (int i = 0; i < 4; ++i)
        tile[r + i * 8][c] = in[(size_t)(k0 + r + i * 8) * N + n0 + c];
    __syncthreads();
    #pragma unroll
    for (int i = 0; i < 4; ++i)
        outT[(size_t)(n0 + r + i * 8) * K + k0 + c] = __float2bfloat16(tile[c][r + i * 8]);
}

// ---------------------------------------------------------------------------
// GEMM (m97 structure): C[M][N] = A[M][K] * Bt[N][K]^T. 128x128 tile, BK=32,
// 4 waves each owning a 64x64 subtile. global_load_lds width=16, linear LDS.
// ---------------------------------------------------------------------------
template <typename CT>
__global__ __launch_bounds__(256) void gemm_tn(
    const __hip_bfloat16* __restrict__ A,
    const __hip_bfloat16* __restrict__ Bt,
    CT* __restrict__ C, int M, int N, int K)
{
    __shared__ __hip_bfloat16 As[128 * 32];
    __shared__ __hip_bfloat16 Bs[128 * 32];

    const int tid  = threadIdx.x;
    const int lane = tid & 63;
    const int wr   = (tid >> 6) >> 1;   // wave row (0..1)
    const int wc   = (tid >> 6) & 1;    // wave col (0..1)
    const int m0 = blockIdx.y * 128;
    const int n0 = blockIdx.x * 128;

    f32x4 acc[4][4] = {};

    // staging: inst p covers elems [(p*256+tid)*8 .. +8): row=idx/32, col=idx%32
    const int s0 = tid * 8,          sr0 = s0 >> 5, sc0 = s0 & 31;
    const int s1 = (256 + tid) * 8,  sr1 = s1 >> 5, sc1 = s1 & 31;

    const int fr = lane & 15;          // fragment row/col within 16
    const int kf = (lane >> 4) * 8;    // k-chunk

    for (int kk = 0; kk < K; kk += 32) {
        GLOAD16(A  + (size_t)(m0 + sr0) * K + kk + sc0, &As[s0]);
        GLOAD16(A  + (size_t)(m0 + sr1) * K + kk + sc1, &As[s1]);
        GLOAD16(Bt + (size_t)(n0 + sr0) * K + kk + sc0, &Bs[s0]);
        GLOAD16(Bt + (size_t)(n0 + sr1) * K + kk + sc1, &Bs[s1]);
        __syncthreads();

        short8 a[4], b[4];
        #pragma unroll
        for (int m = 0; m < 4; ++m)
            a[m] = *reinterpret_cast<const short8*>(&As[(wr * 64 + m * 16 + fr) * 32 + kf]);
        #pragma unroll
        for (int n = 0; n < 4; ++n)
            b[n] = *reinterpret_cast<const short8*>(&Bs[(wc * 64 + n * 16 + fr) * 32 + kf]);
        #pragma unroll
        for (int m = 0; m < 4; ++m)
            #pragma unroll
            for (int n = 0; n < 4; ++n)
                acc[m][n] = __builtin_amdgcn_mfma_f32_16x16x32_bf16(a[m], b[n], acc[m][n], 0, 0, 0);
        __syncthreads();
    }

    const int rowb = m0 + wr * 64 + (lane >> 4) * 4;
    const int colb = n0 + wc * 64 + fr;
    #pragma unroll
    for (int m = 0; m < 4; ++m)
        #pragma unroll
        for (int n = 0; n < 4; ++n)
            #pragma unroll
            for (int r = 0; r < 4; ++r) {
                float v = acc[m][n][r];
                if constexpr (__is_same(CT, float))
                    C[(size_t)(rowb + m * 16 + r) * N + colb + n * 16] = v;
                else
                    C[(size_t)(rowb + m * 16 + r) * N + colb + n * 16] = __float2bfloat16(v);
            }
}

// ---------------------------------------------------------------------------
// L2-normalize q and k head vectors in-place.
// ---------------------------------------------------------------------------
__global__ __launch_bounds__(256) void l2norm_qk(__hip_bfloat16* __restrict__ qkv)
{
    const int lane = threadIdx.x & 63;
    const int wid  = threadIdx.x >> 6;
    const int vec  = blockIdx.x * 4 + wid;

    size_t base;
    if (vec < B_ * T_ * H_) {
        int bt = vec >> 4, h = vec & 15;
        base = (size_t)bt * QKVW + h * HD_;
    } else {
        int v = vec - B_ * T_ * H_;
        int bt = v >> 2, g = v & 3;
        base = (size_t)bt * QKVW + H_ * HD_ + g * HD_;
    }

    float val = __bfloat162float(qkv[base + lane]);
    float s = val * val;
    #pragma unroll
    for (int off = 32; off; off >>= 1) s += __shfl_xor(s, off, 64);
    float scale = 1.0f / (sqrtf(s) + 1e-10f);
    qkv[base + lane] = __float2bfloat16(val * scale);
}

// ---------------------------------------------------------------------------
// Build transposed V: vt[(b*G+g)*64 + d][t] = v[b][t][g][d] (from qkv buffer).
// ---------------------------------------------------------------------------
__global__ __launch_bounds__(256) void vt_build(
    const __hip_bfloat16* __restrict__ qkv, __hip_bfloat16* __restrict__ vt)
{
    __shared__ __hip_bfloat16 tile[32][33];
    const int t0 = blockIdx.x * 32;
    const int d0 = blockIdx.y * 32;
    const int bg = blockIdx.z;          // b*G + g
    const int r = threadIdx.x >> 5, c = threadIdx.x & 31;
    #pragma unroll
    for (int i = 0; i < 4; ++i)
        tile[r + i * 8][c] = qkv[((size_t)((bg >> 2) * T_ + t0 + r + i * 8)) * QKVW
                                 + (H_ + G_) * HD_ + (bg & 3) * HD_ + d0 + c];
    __syncthreads();
    #pragma unroll
    for (int i = 0; i < 4; ++i)
        vt[((size_t)(bg * HD_ + d0 + r + i * 8)) * T_ + t0 + c] = tile[c][r + i * 8];
}

// ---------------------------------------------------------------------------
// Flash attention, causal, GQA. Block = 4 waves, two paired q-tiles
// (qt, 15-qt) for uniform work. K from qkv, V from precomputed vt.
// ---------------------------------------------------------------------------
__global__ __launch_bounds__(256) void attn_fwd(
    const __hip_bfloat16* __restrict__ qkv,
    const __hip_bfloat16* __restrict__ vt,
    __hip_bfloat16* __restrict__ out)   // [B,T,H*HD]
{
    const int pair = blockIdx.x;        // 0..7
    const int h  = blockIdx.y;
    const int b  = blockIdx.z;
    const int g  = h >> 2;

    const int tid  = threadIdx.x;
    const int lane = tid & 63;
    const int wid  = tid >> 6;

    __shared__ __hip_bfloat16 Ks[64][88];       // K rows x dims
    __shared__ __hip_bfloat16 Vs[64][88];       // Vs[d][k-row]
    __shared__ __hip_bfloat16 Ps[4][16][88];

    const int kf = (lane >> 4) * 8;
    const int fr = lane & 15;
    const float scale = 0.125f;

    // staging decomposition: 2 iters of 2048 elems; row=idx/64, col=idx%64
    const int s0 = tid * 8,          sr0 = s0 >> 6, sc0 = s0 & 63;
    const int s1 = (256 + tid) * 8,  sr1 = s1 >> 6, sc1 = s1 & 63;

    const size_t krow0 = (size_t)(b * T_ + sr0) * QKVW + H_ * HD_ + g * HD_ + sc0;
    const size_t krow1 = (size_t)(b * T_ + sr1) * QKVW + H_ * HD_ + g * HD_ + sc1;
    const size_t vrow0 = (size_t)((b * G_ + g) * HD_ + sr0) * T_ + sc0;
    const size_t vrow1 = (size_t)((b * G_ + g) * HD_ + sr1) * T_ + sc1;

    for (int half = 0; half < 2; ++half) {
        const int qt = half ? (15 - pair) : pair;
        const int q0 = qt * 64;
        const int arow  = q0 + wid * 16 + fr;
        const int rbase = q0 + wid * 16 + (lane >> 4) * 4;

        short8 qfrag0, qfrag1;
        {
            const size_t qbase = ((size_t)(b * T_ + arow)) * QKVW + h * HD_;
            qfrag0 = *reinterpret_cast<const short8*>(qkv + qbase + kf);
            qfrag1 = *reinterpret_cast<const short8*>(qkv + qbase + 32 + kf);
        }

        float m[4], l[4];
        f32x4 o[4] = {};
        #pragma unroll
        for (int r = 0; r < 4; ++r) { m[r] = -INFINITY; l[r] = 0.f; }

        for (int kt = 0; kt <= qt; ++kt) {
            const size_t koff = (size_t)(kt * 64) * QKVW;
            *reinterpret_cast<short8*>(&Ks[sr0][sc0]) =
                *reinterpret_cast<const short8*>(qkv + krow0 + koff);
            *reinterpret_cast<short8*>(&Ks[sr1][sc1]) =
                *reinterpret_cast<const short8*>(qkv + krow1 + koff);
            *reinterpret_cast<short8*>(&Vs[sr0][sc0]) =
                *reinterpret_cast<const short8*>(vt + vrow0 + kt * 64);
            *reinterpret_cast<short8*>(&Vs[sr1][sc1]) =
                *reinterpret_cast<const short8*>(vt + vrow1 + kt * 64);
            __syncthreads();

            // ---- S = Q K^T ----
            f32x4 s[4] = {};
            #pragma unroll
            for (int nf = 0; nf < 4; ++nf) {
                short8 b0 = *reinterpret_cast<const short8*>(&Ks[fr + 16 * nf][kf]);
                short8 b1 = *reinterpret_cast<const short8*>(&Ks[fr + 16 * nf][32 + kf]);
                s[nf] = __builtin_amdgcn_mfma_f32_16x16x32_bf16(qfrag0, b0, s[nf], 0, 0, 0);
                s[nf] = __builtin_amdgcn_mfma_f32_16x16x32_bf16(qfrag1, b1, s[nf], 0, 0, 0);
            }

            // ---- scale + causal mask + row max ----
            float rowmax[4] = {-INFINITY, -INFINITY, -INFINITY, -INFINITY};
            #pragma unroll
            for (int nf = 0; nf < 4; ++nf) {
                int col = kt * 64 + fr + 16 * nf;
                #pragma unroll
                for (int r = 0; r < 4; ++r) {
                    float v = s[nf][r] * scale;
                    v = (col <= rbase + r) ? v : -1e9f;
                    s[nf][r] = v;
                    rowmax[r] = fmaxf(rowmax[r], v);
                }
            }
            #pragma unroll
            for (int r = 0; r < 4; ++r) {
                float v = rowmax[r];
                v = fmaxf(v, __shfl_xor(v, 1, 64));
                v = fmaxf(v, __shfl_xor(v, 2, 64));
                v = fmaxf(v, __shfl_xor(v, 4, 64));
                v = fmaxf(v, __shfl_xor(v, 8, 64));
                rowmax[r] = v;
            }

            float alpha[4];
            #pragma unroll
            for (int r = 0; r < 4; ++r) {
                float mn = fmaxf(m[r], rowmax[r]);
                alpha[r] = __expf(m[r] - mn);
                m[r] = mn;
            }
            float rowsum[4] = {0.f, 0.f, 0.f, 0.f};
            #pragma unroll
            for (int nf = 0; nf < 4; ++nf) {
                #pragma unroll
                for (int r = 0; r < 4; ++r) {
                    float p = __expf(s[nf][r] - m[r]);
                    s[nf][r] = p;
                    rowsum[r] += p;
                }
            }
            #pragma unroll
            for (int r = 0; r < 4; ++r) {
                float v = rowsum[r];
                v += __shfl_xor(v, 1, 64);
                v += __shfl_xor(v, 2, 64);
                v += __shfl_xor(v, 4, 64);
                v += __shfl_xor(v, 8, 64);
                l[r] = l[r] * alpha[r] + v;
            }

            #pragma unroll
            for (int nf = 0; nf < 4; ++nf)
                #pragma unroll
                for (int r = 0; r < 4; ++r)
                    Ps[wid][(lane >> 4) * 4 + r][fr + 16 * nf] = __float2bfloat16(s[nf][r]);
            #pragma unroll
            for (int nf = 0; nf < 4; ++nf)
                #pragma unroll
                for (int r = 0; r < 4; ++r)
                    o[nf][r] *= alpha[r];

            short8 pa0 = *reinterpret_cast<const short8*>(&Ps[wid][fr][kf]);
            short8 pa1 = *reinterpret_cast<const short8*>(&Ps[wid][fr][32 + kf]);
            #pragma unroll
            for (int nf = 0; nf < 4; ++nf) {
                short8 b0 = *reinterpret_cast<const short8*>(&Vs[fr + 16 * nf][kf]);
                short8 b1 = *reinterpret_cast<const short8*>(&Vs[fr + 16 * nf][32 + kf]);
                o[nf] = __builtin_amdgcn_mfma_f32_16x16x32_bf16(pa0, b0, o[nf], 0, 0, 0);
                o[nf] = __builtin_amdgcn_mfma_f32_16x16x32_bf16(pa1, b1, o[nf], 0, 0, 0);
            }
            __syncthreads();
        }

        #pragma unroll
        for (int nf = 0; nf < 4; ++nf) {
            int col = fr + 16 * nf;
            #pragma unroll
            for (int r = 0; r < 4; ++r) {
                float v = o[nf][r] / l[r];
                out[((size_t)(b * T_ + rbase + r)) * (H_ * HD_) + h * HD_ + col] =
                    __float2bfloat16(v);
            }
        }
    }
}

extern "C" void kernel_launch(void* const* d_in, const int* in_sizes, int n_in,
                              void* d_out, int out_size, void* d_ws, size_t ws_size,
                              hipStream_t stream) {
    const float* x_f     = (const float*)d_in[0];   // [8192,1024]
    const float* w_qkv_f = (const float*)d_in[1];   // [1024,1536]
    const float* w_o_f   = (const float*)d_in[2];   // [1024,1024]
    float* out = (float*)d_out;

    const int NX  = B_ * T_ * D_;      // 8388608
    const int NWQ = D_ * QKVW;         // 1572864
    const int NWO = D_ * D_;           // 1048576

    __hip_bfloat16* xb    = (__hip_bfloat16*)d_ws;                 // [8192][1024], reused as attn_out
    __hip_bfloat16* wqkvT = xb + NX;                               // [1536][1024]
    __hip_bfloat16* woT   = wqkvT + NWQ;                           // [1024][1024]
    __hip_bfloat16* qkv   = woT + NWO;                             // [8192][1536]
    __hip_bfloat16* vt    = qkv + (size_t)(B_ * T_) * QKVW;        // [B*G*64][1024]
    __hip_bfloat16* attn_out = xb;   // alias: xb dead after gemm1

    dim3 blk(256);

    // 0) conversions (+ weight transposes)
    cvt_f32_bf16<<<dim3(NX / 2048), blk, 0, stream>>>(x_f, xb, NX);
    cvt_transpose<<<dim3(QKVW / 32, D_ / 32), blk, 0, stream>>>(w_qkv_f, wqkvT, D_, QKVW);
    cvt_transpose<<<dim3(D_ / 32, D_ / 32), blk, 0, stream>>>(w_o_f, woT, D_, D_);

    // 1) qkv = x @ w_qkv
    gemm_tn<__hip_bfloat16><<<dim3(QKVW / 128, (B_ * T_) / 128), blk, 0, stream>>>(
        xb, wqkvT, qkv, B_ * T_, QKVW, D_);

    // 2) L2-normalize q,k
    l2norm_qk<<<dim3((B_ * T_ * H_ + B_ * T_ * G_) / 4), blk, 0, stream>>>(qkv);

    // 3) transposed V
    vt_build<<<dim3(T_ / 32, HD_ / 32, B_ * G_), blk, 0, stream>>>(qkv, vt);

    // 4) flash attention
    attn_fwd<<<dim3(8, H_, B_), blk, 0, stream>>>(qkv, vt, attn_out);

    // 5) out = attn_out @ w_o -> fp32
    gemm_tn<float><<<dim3(D_ / 128, (B_ * T_) / 128), blk, 0, stream>>>(
        attn_out, woT, out, B_ * T_, D_, D_);
}

// Round 5
// 151.909 us; speedup vs baseline: 2.5002x; 1.2305x over previous
//
#include <hip/hip_runtime.h>
#include <hip/hip_bf16.h>

typedef __attribute__((ext_vector_type(8))) short short8;
typedef __attribute__((ext_vector_type(4))) float f32x4;

#define B_ 8
#define T_ 1024
#define D_ 1024
#define H_ 16
#define G_ 4
#define HD_ 64
#define QKVW 1536   // H*HD + 2*G*HD

#define GLOAD16(gp, lp) __builtin_amdgcn_global_load_lds( \
    (const __attribute__((address_space(1))) void*)(gp),  \
    (__attribute__((address_space(3))) void*)(lp), 16, 0, 0)

// fast 2^x on gfx950 (v_exp_f32); __exp2f does not exist in this toolchain
__device__ __forceinline__ float exp2_fast(float x) {
    return __builtin_amdgcn_exp2f(x);
}

// ---------------------------------------------------------------------------
// fp32 -> bf16 conversion, 8 elems/thread.
// ---------------------------------------------------------------------------
__global__ __launch_bounds__(256) void cvt_f32_bf16(
    const float* __restrict__ in, __hip_bfloat16* __restrict__ out, int n)
{
    int i = (blockIdx.x * 256 + threadIdx.x) * 8;
    if (i >= n) return;
    float4 a = *reinterpret_cast<const float4*>(in + i);
    float4 b = *reinterpret_cast<const float4*>(in + i + 4);
    union { short8 s; __hip_bfloat16 h[8]; } u;
    u.h[0] = __float2bfloat16(a.x); u.h[1] = __float2bfloat16(a.y);
    u.h[2] = __float2bfloat16(a.z); u.h[3] = __float2bfloat16(a.w);
    u.h[4] = __float2bfloat16(b.x); u.h[5] = __float2bfloat16(b.y);
    u.h[6] = __float2bfloat16(b.z); u.h[7] = __float2bfloat16(b.w);
    *reinterpret_cast<short8*>(out + i) = u.s;
}

// ---------------------------------------------------------------------------
// fp32 [K][N] -> bf16 transposed [N][K], LDS-tiled 32x32.
// ---------------------------------------------------------------------------
__global__ __launch_bounds__(256) void cvt_transpose(
    const float* __restrict__ in, __hip_bfloat16* __restrict__ outT, int K, int N)
{
    __shared__ float tile[32][33];
    const int k0 = blockIdx.y * 32, n0 = blockIdx.x * 32;
    const int r = threadIdx.x >> 5, c = threadIdx.x & 31;
    #pragma unroll
    for (int i = 0; i < 4; ++i)
        tile[r + i * 8][c] = in[(size_t)(k0 + r + i * 8) * N + n0 + c];
    __syncthreads();
    #pragma unroll
    for (int i = 0; i < 4; ++i)
        outT[(size_t)(n0 + r + i * 8) * K + k0 + c] = __float2bfloat16(tile[c][r + i * 8]);
}

// ---------------------------------------------------------------------------
// GEMM (m97 structure): C[M][N] = A[M][K] * Bt[N][K]^T. 128x128 tile, BK=32,
// 4 waves each owning a 64x64 subtile. global_load_lds width=16, linear LDS.
// 1D grid with bijective XCD band swizzle (requires grid%8==0).
// ---------------------------------------------------------------------------
template <typename CT>
__global__ __launch_bounds__(256) void gemm_tn(
    const __hip_bfloat16* __restrict__ A,
    const __hip_bfloat16* __restrict__ Bt,
    CT* __restrict__ C, int M, int N, int K)
{
    __shared__ __hip_bfloat16 As[128 * 32];
    __shared__ __hip_bfloat16 Bs[128 * 32];

    const int tid  = threadIdx.x;
    const int lane = tid & 63;
    const int wr   = (tid >> 6) >> 1;
    const int wc   = (tid >> 6) & 1;

    // XCD swizzle: each XCD gets an 8-m-row band, m fastest within band.
    const int NBY = M >> 7;
    const int rpx = NBY >> 3;                // m-blocks per XCD band
    const int xcd = blockIdx.x & 7;
    const int lin = blockIdx.x >> 3;
    const int by  = xcd * rpx + (lin % rpx);
    const int bx  = lin / rpx;
    const int m0 = by * 128;
    const int n0 = bx * 128;

    f32x4 acc[4][4] = {};

    const int s0 = tid * 8,          sr0 = s0 >> 5, sc0 = s0 & 31;
    const int s1 = (256 + tid) * 8,  sr1 = s1 >> 5, sc1 = s1 & 31;

    const int fr = lane & 15;
    const int kf = (lane >> 4) * 8;

    for (int kk = 0; kk < K; kk += 32) {
        GLOAD16(A  + (size_t)(m0 + sr0) * K + kk + sc0, &As[s0]);
        GLOAD16(A  + (size_t)(m0 + sr1) * K + kk + sc1, &As[s1]);
        GLOAD16(Bt + (size_t)(n0 + sr0) * K + kk + sc0, &Bs[s0]);
        GLOAD16(Bt + (size_t)(n0 + sr1) * K + kk + sc1, &Bs[s1]);
        __syncthreads();

        short8 a[4], b[4];
        #pragma unroll
        for (int m = 0; m < 4; ++m)
            a[m] = *reinterpret_cast<const short8*>(&As[(wr * 64 + m * 16 + fr) * 32 + kf]);
        #pragma unroll
        for (int n = 0; n < 4; ++n)
            b[n] = *reinterpret_cast<const short8*>(&Bs[(wc * 64 + n * 16 + fr) * 32 + kf]);
        #pragma unroll
        for (int m = 0; m < 4; ++m)
            #pragma unroll
            for (int n = 0; n < 4; ++n)
                acc[m][n] = __builtin_amdgcn_mfma_f32_16x16x32_bf16(a[m], b[n], acc[m][n], 0, 0, 0);
        __syncthreads();
    }

    const int rowb = m0 + wr * 64 + (lane >> 4) * 4;
    const int colb = n0 + wc * 64 + fr;
    #pragma unroll
    for (int m = 0; m < 4; ++m)
        #pragma unroll
        for (int n = 0; n < 4; ++n)
            #pragma unroll
            for (int r = 0; r < 4; ++r) {
                float v = acc[m][n][r];
                if constexpr (__is_same(CT, float))
                    C[(size_t)(rowb + m * 16 + r) * N + colb + n * 16] = v;
                else
                    C[(size_t)(rowb + m * 16 + r) * N + colb + n * 16] = __float2bfloat16(v);
            }
}

// ---------------------------------------------------------------------------
// L2-normalize q and k head vectors in-place.
// ---------------------------------------------------------------------------
__global__ __launch_bounds__(256) void l2norm_qk(__hip_bfloat16* __restrict__ qkv)
{
    const int lane = threadIdx.x & 63;
    const int wid  = threadIdx.x >> 6;
    const int vec  = blockIdx.x * 4 + wid;

    size_t base;
    if (vec < B_ * T_ * H_) {
        int bt = vec >> 4, h = vec & 15;
        base = (size_t)bt * QKVW + h * HD_;
    } else {
        int v = vec - B_ * T_ * H_;
        int bt = v >> 2, g = v & 3;
        base = (size_t)bt * QKVW + H_ * HD_ + g * HD_;
    }

    float val = __bfloat162float(qkv[base + lane]);
    float s = val * val;
    #pragma unroll
    for (int off = 32; off; off >>= 1) s += __shfl_xor(s, off, 64);
    float scale = 1.0f / (sqrtf(s) + 1e-10f);
    qkv[base + lane] = __float2bfloat16(val * scale);
}

// ---------------------------------------------------------------------------
// Build transposed V: vt[(b*G+g)*64 + d][t] = v[b][t][g][d].
// ---------------------------------------------------------------------------
__global__ __launch_bounds__(256) void vt_build(
    const __hip_bfloat16* __restrict__ qkv, __hip_bfloat16* __restrict__ vt)
{
    __shared__ __hip_bfloat16 tile[32][33];
    const int t0 = blockIdx.x * 32;
    const int d0 = blockIdx.y * 32;
    const int bg = blockIdx.z;
    const int r = threadIdx.x >> 5, c = threadIdx.x & 31;
    #pragma unroll
    for (int i = 0; i < 4; ++i)
        tile[r + i * 8][c] = qkv[((size_t)((bg >> 2) * T_ + t0 + r + i * 8)) * QKVW
                                 + (H_ + G_) * HD_ + (bg & 3) * HD_ + d0 + c];
    __syncthreads();
    #pragma unroll
    for (int i = 0; i < 4; ++i)
        vt[((size_t)(bg * HD_ + d0 + r + i * 8)) * T_ + t0 + c] = tile[c][r + i * 8];
}

// ---------------------------------------------------------------------------
// Flash attention, causal, GQA. q,k are L2-normalized so |s|<=0.126 -> exp
// never overflows -> NO max tracking, NO per-tile rescale, row-sum deferred
// to a single post-loop reduce. Block = 4 waves, paired q-tiles (qt, 15-qt).
// ---------------------------------------------------------------------------
__global__ __launch_bounds__(256) void attn_fwd(
    const __hip_bfloat16* __restrict__ qkv,
    const __hip_bfloat16* __restrict__ vt,
    __hip_bfloat16* __restrict__ out)   // [B,T,H*HD]
{
    const int pair = blockIdx.x;        // 0..7
    const int h  = blockIdx.y;
    const int b  = blockIdx.z;
    const int g  = h >> 2;

    const int tid  = threadIdx.x;
    const int lane = tid & 63;
    const int wid  = tid >> 6;

    __shared__ __hip_bfloat16 Ks[64][88];
    __shared__ __hip_bfloat16 Vs[64][88];
    __shared__ __hip_bfloat16 Ps[4][16][88];

    const int kf = (lane >> 4) * 8;
    const int fr = lane & 15;
    // exp(s*0.125) = exp2(s * 0.125 * log2(e))
    const float EC = 0.125f * 1.44269504f;

    const int s0 = tid * 8,          sr0 = s0 >> 6, sc0 = s0 & 63;
    const int s1 = (256 + tid) * 8,  sr1 = s1 >> 6, sc1 = s1 & 63;

    const size_t krow0 = (size_t)(b * T_ + sr0) * QKVW + H_ * HD_ + g * HD_ + sc0;
    const size_t krow1 = (size_t)(b * T_ + sr1) * QKVW + H_ * HD_ + g * HD_ + sc1;
    const size_t vrow0 = (size_t)((b * G_ + g) * HD_ + sr0) * T_ + sc0;
    const size_t vrow1 = (size_t)((b * G_ + g) * HD_ + sr1) * T_ + sc1;

    for (int half = 0; half < 2; ++half) {
        const int qt = half ? (15 - pair) : pair;
        const int q0 = qt * 64;
        const int arow  = q0 + wid * 16 + fr;
        const int rbase = q0 + wid * 16 + (lane >> 4) * 4;

        short8 qfrag0, qfrag1;
        {
            const size_t qbase = ((size_t)(b * T_ + arow)) * QKVW + h * HD_;
            qfrag0 = *reinterpret_cast<const short8*>(qkv + qbase + kf);
            qfrag1 = *reinterpret_cast<const short8*>(qkv + qbase + 32 + kf);
        }

        float lsum[4] = {0.f, 0.f, 0.f, 0.f};
        f32x4 o[4] = {};

        for (int kt = 0; kt <= qt; ++kt) {
            const bool diag = (kt == qt);
            // ---- stage K tile + V tile ----
            const size_t koff = (size_t)(kt * 64) * QKVW;
            *reinterpret_cast<short8*>(&Ks[sr0][sc0]) =
                *reinterpret_cast<const short8*>(qkv + krow0 + koff);
            *reinterpret_cast<short8*>(&Ks[sr1][sc1]) =
                *reinterpret_cast<const short8*>(qkv + krow1 + koff);
            *reinterpret_cast<short8*>(&Vs[sr0][sc0]) =
                *reinterpret_cast<const short8*>(vt + vrow0 + kt * 64);
            *reinterpret_cast<short8*>(&Vs[sr1][sc1]) =
                *reinterpret_cast<const short8*>(vt + vrow1 + kt * 64);
            __syncthreads();

            // ---- S = Q K^T ----
            f32x4 s[4] = {};
            #pragma unroll
            for (int nf = 0; nf < 4; ++nf) {
                short8 b0 = *reinterpret_cast<const short8*>(&Ks[fr + 16 * nf][kf]);
                short8 b1 = *reinterpret_cast<const short8*>(&Ks[fr + 16 * nf][32 + kf]);
                s[nf] = __builtin_amdgcn_mfma_f32_16x16x32_bf16(qfrag0, b0, s[nf], 0, 0, 0);
                s[nf] = __builtin_amdgcn_mfma_f32_16x16x32_bf16(qfrag1, b1, s[nf], 0, 0, 0);
            }

            // ---- p = exp(s*scale) (0 where masked on diagonal tile) ----
            if (diag) {
                #pragma unroll
                for (int nf = 0; nf < 4; ++nf) {
                    int col = kt * 64 + fr + 16 * nf;
                    #pragma unroll
                    for (int r = 0; r < 4; ++r) {
                        float p = (col <= rbase + r) ? exp2_fast(s[nf][r] * EC) : 0.f;
                        lsum[r] += p;
                        Ps[wid][(lane >> 4) * 4 + r][fr + 16 * nf] = __float2bfloat16(p);
                    }
                }
            } else {
                #pragma unroll
                for (int nf = 0; nf < 4; ++nf)
                    #pragma unroll
                    for (int r = 0; r < 4; ++r) {
                        float p = exp2_fast(s[nf][r] * EC);
                        lsum[r] += p;
                        Ps[wid][(lane >> 4) * 4 + r][fr + 16 * nf] = __float2bfloat16(p);
                    }
            }

            // ---- O += P V ----
            short8 pa0 = *reinterpret_cast<const short8*>(&Ps[wid][fr][kf]);
            short8 pa1 = *reinterpret_cast<const short8*>(&Ps[wid][fr][32 + kf]);
            #pragma unroll
            for (int nf = 0; nf < 4; ++nf) {
                short8 b0 = *reinterpret_cast<const short8*>(&Vs[fr + 16 * nf][kf]);
                short8 b1 = *reinterpret_cast<const short8*>(&Vs[fr + 16 * nf][32 + kf]);
                o[nf] = __builtin_amdgcn_mfma_f32_16x16x32_bf16(pa0, b0, o[nf], 0, 0, 0);
                o[nf] = __builtin_amdgcn_mfma_f32_16x16x32_bf16(pa1, b1, o[nf], 0, 0, 0);
            }
            __syncthreads();
        }

        // ---- single deferred row-sum reduce + epilogue ----
        float linv[4];
        #pragma unroll
        for (int r = 0; r < 4; ++r) {
            float v = lsum[r];
            v += __shfl_xor(v, 1, 64);
            v += __shfl_xor(v, 2, 64);
            v += __shfl_xor(v, 4, 64);
            v += __shfl_xor(v, 8, 64);
            linv[r] = 1.0f / v;
        }
        #pragma unroll
        for (int nf = 0; nf < 4; ++nf) {
            int col = fr + 16 * nf;
            #pragma unroll
            for (int r = 0; r < 4; ++r) {
                float v = o[nf][r] * linv[r];
                out[((size_t)(b * T_ + rbase + r)) * (H_ * HD_) + h * HD_ + col] =
                    __float2bfloat16(v);
            }
        }
    }
}

extern "C" void kernel_launch(void* const* d_in, const int* in_sizes, int n_in,
                              void* d_out, int out_size, void* d_ws, size_t ws_size,
                              hipStream_t stream) {
    const float* x_f     = (const float*)d_in[0];   // [8192,1024]
    const float* w_qkv_f = (const float*)d_in[1];   // [1024,1536]
    const float* w_o_f   = (const float*)d_in[2];   // [1024,1024]
    float* out = (float*)d_out;

    const int NX  = B_ * T_ * D_;
    const int NWQ = D_ * QKVW;
    const int NWO = D_ * D_;

    __hip_bfloat16* xb    = (__hip_bfloat16*)d_ws;
    __hip_bfloat16* wqkvT = xb + NX;
    __hip_bfloat16* woT   = wqkvT + NWQ;
    __hip_bfloat16* qkv   = woT + NWO;
    __hip_bfloat16* vt    = qkv + (size_t)(B_ * T_) * QKVW;
    __hip_bfloat16* attn_out = xb;   // alias: xb dead after gemm1

    dim3 blk(256);

    cvt_f32_bf16<<<dim3(NX / 2048), blk, 0, stream>>>(x_f, xb, NX);
    cvt_transpose<<<dim3(QKVW / 32, D_ / 32), blk, 0, stream>>>(w_qkv_f, wqkvT, D_, QKVW);
    cvt_transpose<<<dim3(D_ / 32, D_ / 32), blk, 0, stream>>>(w_o_f, woT, D_, D_);

    // 1) qkv = x @ w_qkv  (grid = 12*64 = 768, %8==0)
    gemm_tn<__hip_bfloat16><<<dim3((QKVW / 128) * ((B_ * T_) / 128)), blk, 0, stream>>>(
        xb, wqkvT, qkv, B_ * T_, QKVW, D_);

    l2norm_qk<<<dim3((B_ * T_ * H_ + B_ * T_ * G_) / 4), blk, 0, stream>>>(qkv);

    vt_build<<<dim3(T_ / 32, HD_ / 32, B_ * G_), blk, 0, stream>>>(qkv, vt);

    attn_fwd<<<dim3(8, H_, B_), blk, 0, stream>>>(qkv, vt, attn_out);

    // 5) out = attn_out @ w_o  (grid = 8*64 = 512, %8==0)
    gemm_tn<float><<<dim3((D_ / 128) * ((B_ * T_) / 128)), blk, 0, stream>>>(
        attn_out, woT, out, B_ * T_, D_, D_);
}

// Round 6
// 136.621 us; speedup vs baseline: 2.7800x; 1.1119x over previous
//
#include <hip/hip_runtime.h>
#include <hip/hip_bf16.h>

typedef __attribute__((ext_vector_type(8))) short short8;
typedef __attribute__((ext_vector_type(4))) float f32x4;

#define B_ 8
#define T_ 1024
#define D_ 1024
#define H_ 16
#define G_ 4
#define HD_ 64
#define QKVW 1536   // H*HD + 2*G*HD

#define GLOAD16(gp, lp) __builtin_amdgcn_global_load_lds( \
    (const __attribute__((address_space(1))) void*)(gp),  \
    (__attribute__((address_space(3))) void*)(lp), 16, 0, 0)

// fast 2^x on gfx950 (v_exp_f32)
__device__ __forceinline__ float exp2_fast(float x) {
    return __builtin_amdgcn_exp2f(x);
}

// ---------------------------------------------------------------------------
// fp32 -> bf16 conversion, 8 elems/thread.
// ---------------------------------------------------------------------------
__global__ __launch_bounds__(256) void cvt_f32_bf16(
    const float* __restrict__ in, __hip_bfloat16* __restrict__ out, int n)
{
    int i = (blockIdx.x * 256 + threadIdx.x) * 8;
    if (i >= n) return;
    float4 a = *reinterpret_cast<const float4*>(in + i);
    float4 b = *reinterpret_cast<const float4*>(in + i + 4);
    union { short8 s; __hip_bfloat16 h[8]; } u;
    u.h[0] = __float2bfloat16(a.x); u.h[1] = __float2bfloat16(a.y);
    u.h[2] = __float2bfloat16(a.z); u.h[3] = __float2bfloat16(a.w);
    u.h[4] = __float2bfloat16(b.x); u.h[5] = __float2bfloat16(b.y);
    u.h[6] = __float2bfloat16(b.z); u.h[7] = __float2bfloat16(b.w);
    *reinterpret_cast<short8*>(out + i) = u.s;
}

// ---------------------------------------------------------------------------
// fp32 [K][N] -> bf16 transposed [N][K], LDS-tiled 32x32.
// ---------------------------------------------------------------------------
__global__ __launch_bounds__(256) void cvt_transpose(
    const float* __restrict__ in, __hip_bfloat16* __restrict__ outT, int K, int N)
{
    __shared__ float tile[32][33];
    const int k0 = blockIdx.y * 32, n0 = blockIdx.x * 32;
    const int r = threadIdx.x >> 5, c = threadIdx.x & 31;
    #pragma unroll
    for (int i = 0; i < 4; ++i)
        tile[r + i * 8][c] = in[(size_t)(k0 + r + i * 8) * N + n0 + c];
    __syncthreads();
    #pragma unroll
    for (int i = 0; i < 4; ++i)
        outT[(size_t)(n0 + r + i * 8) * K + k0 + c] = __float2bfloat16(tile[c][r + i * 8]);
}

// ---------------------------------------------------------------------------
// GEMM: C[M][N] = A[M][K] * Bt[N][K]^T. 128x128 tile, BK=32, 4 waves,
// global_load_lds width=16, 2-phase LDS double-buffer: prefetch next K-tile
// during current compute, ONE barrier per K-step. XCD band swizzle.
// ---------------------------------------------------------------------------
template <typename CT>
__global__ __launch_bounds__(256) void gemm_tn(
    const __hip_bfloat16* __restrict__ A,
    const __hip_bfloat16* __restrict__ Bt,
    CT* __restrict__ C, int M, int N, int K)
{
    __shared__ __hip_bfloat16 As[2][128 * 32];
    __shared__ __hip_bfloat16 Bs[2][128 * 32];

    const int tid  = threadIdx.x;
    const int lane = tid & 63;
    const int wr   = (tid >> 6) >> 1;
    const int wc   = (tid >> 6) & 1;

    const int NBY = M >> 7;
    const int rpx = NBY >> 3;
    const int xcd = blockIdx.x & 7;
    const int lin = blockIdx.x >> 3;
    const int by  = xcd * rpx + (lin % rpx);
    const int bx  = lin / rpx;
    const int m0 = by * 128;
    const int n0 = bx * 128;

    f32x4 acc[4][4] = {};

    const int s0 = tid * 8,          sr0 = s0 >> 5, sc0 = s0 & 31;
    const int s1 = (256 + tid) * 8,  sr1 = s1 >> 5, sc1 = s1 & 31;

    const __hip_bfloat16* Ar0 = A  + (size_t)(m0 + sr0) * K + sc0;
    const __hip_bfloat16* Ar1 = A  + (size_t)(m0 + sr1) * K + sc1;
    const __hip_bfloat16* Br0 = Bt + (size_t)(n0 + sr0) * K + sc0;
    const __hip_bfloat16* Br1 = Bt + (size_t)(n0 + sr1) * K + sc1;

    const int fr = lane & 15;
    const int kf = (lane >> 4) * 8;

    // prologue: stage K-tile 0 into buf 0
    GLOAD16(Ar0, &As[0][s0]);
    GLOAD16(Ar1, &As[0][s1]);
    GLOAD16(Br0, &Bs[0][s0]);
    GLOAD16(Br1, &Bs[0][s1]);
    __syncthreads();

    int cur = 0;
    for (int kk = 0; kk < K; kk += 32) {
        const int nxt = cur ^ 1;
        if (kk + 32 < K) {
            GLOAD16(Ar0 + kk + 32, &As[nxt][s0]);
            GLOAD16(Ar1 + kk + 32, &As[nxt][s1]);
            GLOAD16(Br0 + kk + 32, &Bs[nxt][s0]);
            GLOAD16(Br1 + kk + 32, &Bs[nxt][s1]);
        }
        short8 a[4], b[4];
        #pragma unroll
        for (int m = 0; m < 4; ++m)
            a[m] = *reinterpret_cast<const short8*>(&As[cur][(wr * 64 + m * 16 + fr) * 32 + kf]);
        #pragma unroll
        for (int n = 0; n < 4; ++n)
            b[n] = *reinterpret_cast<const short8*>(&Bs[cur][(wc * 64 + n * 16 + fr) * 32 + kf]);
        #pragma unroll
        for (int m = 0; m < 4; ++m)
            #pragma unroll
            for (int n = 0; n < 4; ++n)
                acc[m][n] = __builtin_amdgcn_mfma_f32_16x16x32_bf16(a[m], b[n], acc[m][n], 0, 0, 0);
        __syncthreads();   // drains prefetch (vmcnt) + protects buf[cur] reuse
        cur = nxt;
    }

    const int rowb = m0 + wr * 64 + (lane >> 4) * 4;
    const int colb = n0 + wc * 64 + fr;
    #pragma unroll
    for (int m = 0; m < 4; ++m)
        #pragma unroll
        for (int n = 0; n < 4; ++n)
            #pragma unroll
            for (int r = 0; r < 4; ++r) {
                float v = acc[m][n][r];
                if constexpr (__is_same(CT, float))
                    C[(size_t)(rowb + m * 16 + r) * N + colb + n * 16] = v;
                else
                    C[(size_t)(rowb + m * 16 + r) * N + colb + n * 16] = __float2bfloat16(v);
            }
}

// ---------------------------------------------------------------------------
// L2-normalize q,k in-place, VECTORIZED: 8 lanes per 64-elem vector, short8
// loads, 3-shuffle 8-lane reduce. q additionally scaled by 0.125*log2(e)
// (folds SDPA scale + exp2 conversion into q, deleting a mul in attention).
// ---------------------------------------------------------------------------
__global__ __launch_bounds__(256) void l2norm_qk(__hip_bfloat16* __restrict__ qkv)
{
    const int tid = threadIdx.x;
    const int vec = blockIdx.x * 32 + (tid >> 3);
    const int j   = tid & 7;
    const int NQ  = B_ * T_ * H_;

    size_t base;
    float extra;
    if (vec < NQ) {                       // q vector
        int bt = vec >> 4, h = vec & 15;
        base = (size_t)bt * QKVW + h * HD_;
        extra = 0.125f * 1.44269504f;     // scale * log2(e)
    } else {                              // k vector
        int v = vec - NQ;
        int bt = v >> 2, g = v & 3;
        base = (size_t)bt * QKVW + H_ * HD_ + g * HD_;
        extra = 1.0f;
    }

    union { short8 s; __hip_bfloat16 h[8]; } u;
    u.s = *reinterpret_cast<const short8*>(qkv + base + j * 8);
    float f[8], ss = 0.f;
    #pragma unroll
    for (int i = 0; i < 8; ++i) { f[i] = __bfloat162float(u.h[i]); ss += f[i] * f[i]; }
    ss += __shfl_xor(ss, 1, 64);
    ss += __shfl_xor(ss, 2, 64);
    ss += __shfl_xor(ss, 4, 64);
    float sc = extra / (sqrtf(ss) + 1e-10f);
    #pragma unroll
    for (int i = 0; i < 8; ++i) u.h[i] = __float2bfloat16(f[i] * sc);
    *reinterpret_cast<short8*>(qkv + base + j * 8) = u.s;
}

// ---------------------------------------------------------------------------
// Build transposed V: vt[(b*G+g)*64 + d][t] = v[b][t][g][d].
// ---------------------------------------------------------------------------
__global__ __launch_bounds__(256) void vt_build(
    const __hip_bfloat16* __restrict__ qkv, __hip_bfloat16* __restrict__ vt)
{
    __shared__ __hip_bfloat16 tile[32][33];
    const int t0 = blockIdx.x * 32;
    const int d0 = blockIdx.y * 32;
    const int bg = blockIdx.z;
    const int r = threadIdx.x >> 5, c = threadIdx.x & 31;
    #pragma unroll
    for (int i = 0; i < 4; ++i)
        tile[r + i * 8][c] = qkv[((size_t)((bg >> 2) * T_ + t0 + r + i * 8)) * QKVW
                                 + (H_ + G_) * HD_ + (bg & 3) * HD_ + d0 + c];
    __syncthreads();
    #pragma unroll
    for (int i = 0; i < 4; ++i)
        vt[((size_t)(bg * HD_ + d0 + r + i * 8)) * T_ + t0 + c] = tile[c][r + i * 8];
}

// ---------------------------------------------------------------------------
// Flash attention, causal, GQA. L2-normalized q,k (scale folded into q) ->
// p = exp2(s) directly, no max tracking, deferred row-sum. T14 async-STAGE:
// next K/V tile prefetched into registers during compute, LDS-written after
// the post-compute barrier. Paired q-tiles (qt, 15-qt).
// ---------------------------------------------------------------------------
__global__ __launch_bounds__(256) void attn_fwd(
    const __hip_bfloat16* __restrict__ qkv,
    const __hip_bfloat16* __restrict__ vt,
    __hip_bfloat16* __restrict__ out)   // [B,T,H*HD]
{
    const int pair = blockIdx.x;        // 0..7
    const int h  = blockIdx.y;
    const int b  = blockIdx.z;
    const int g  = h >> 2;

    const int tid  = threadIdx.x;
    const int lane = tid & 63;
    const int wid  = tid >> 6;

    __shared__ __hip_bfloat16 Ks[64][88];
    __shared__ __hip_bfloat16 Vs[64][88];
    __shared__ __hip_bfloat16 Ps[4][16][88];

    const int kf = (lane >> 4) * 8;
    const int fr = lane & 15;

    const int s0 = tid * 8,          sr0 = s0 >> 6, sc0 = s0 & 63;
    const int s1 = (256 + tid) * 8,  sr1 = s1 >> 6, sc1 = s1 & 63;

    const size_t krow0 = (size_t)(b * T_ + sr0) * QKVW + H_ * HD_ + g * HD_ + sc0;
    const size_t krow1 = (size_t)(b * T_ + sr1) * QKVW + H_ * HD_ + g * HD_ + sc1;
    const size_t vrow0 = (size_t)((b * G_ + g) * HD_ + sr0) * T_ + sc0;
    const size_t vrow1 = (size_t)((b * G_ + g) * HD_ + sr1) * T_ + sc1;

    for (int half = 0; half < 2; ++half) {
        const int qt = half ? (15 - pair) : pair;
        const int q0 = qt * 64;
        const int arow  = q0 + wid * 16 + fr;
        const int rbase = q0 + wid * 16 + (lane >> 4) * 4;

        short8 qfrag0, qfrag1;
        {
            const size_t qbase = ((size_t)(b * T_ + arow)) * QKVW + h * HD_;
            qfrag0 = *reinterpret_cast<const short8*>(qkv + qbase + kf);
            qfrag1 = *reinterpret_cast<const short8*>(qkv + qbase + 32 + kf);
        }

        float lsum[4] = {0.f, 0.f, 0.f, 0.f};
        f32x4 o[4] = {};

        // prologue: stage tile 0
        {
            short8 k0 = *reinterpret_cast<const short8*>(qkv + krow0);
            short8 k1 = *reinterpret_cast<const short8*>(qkv + krow1);
            short8 v0 = *reinterpret_cast<const short8*>(vt + vrow0);
            short8 v1 = *reinterpret_cast<const short8*>(vt + vrow1);
            *reinterpret_cast<short8*>(&Ks[sr0][sc0]) = k0;
            *reinterpret_cast<short8*>(&Ks[sr1][sc1]) = k1;
            *reinterpret_cast<short8*>(&Vs[sr0][sc0]) = v0;
            *reinterpret_cast<short8*>(&Vs[sr1][sc1]) = v1;
        }
        __syncthreads();

        for (int kt = 0; kt <= qt; ++kt) {
            const bool diag = (kt == qt);
            const bool more = (kt < qt);

            // ---- T14: issue next tile's global loads NOW (hide under compute)
            short8 nk0, nk1, nv0, nv1;
            if (more) {
                const size_t koff = (size_t)((kt + 1) * 64) * QKVW;
                nk0 = *reinterpret_cast<const short8*>(qkv + krow0 + koff);
                nk1 = *reinterpret_cast<const short8*>(qkv + krow1 + koff);
                nv0 = *reinterpret_cast<const short8*>(vt + vrow0 + (kt + 1) * 64);
                nv1 = *reinterpret_cast<const short8*>(vt + vrow1 + (kt + 1) * 64);
            }

            // ---- S = Q K^T ----
            f32x4 s[4] = {};
            #pragma unroll
            for (int nf = 0; nf < 4; ++nf) {
                short8 b0 = *reinterpret_cast<const short8*>(&Ks[fr + 16 * nf][kf]);
                short8 b1 = *reinterpret_cast<const short8*>(&Ks[fr + 16 * nf][32 + kf]);
                s[nf] = __builtin_amdgcn_mfma_f32_16x16x32_bf16(qfrag0, b0, s[nf], 0, 0, 0);
                s[nf] = __builtin_amdgcn_mfma_f32_16x16x32_bf16(qfrag1, b1, s[nf], 0, 0, 0);
            }

            // ---- p = exp2(s) (scale pre-folded into q); mask only on diag ----
            if (diag) {
                #pragma unroll
                for (int nf = 0; nf < 4; ++nf) {
                    int col = kt * 64 + fr + 16 * nf;
                    #pragma unroll
                    for (int r = 0; r < 4; ++r) {
                        float p = (col <= rbase + r) ? exp2_fast(s[nf][r]) : 0.f;
                        lsum[r] += p;
                        Ps[wid][(lane >> 4) * 4 + r][fr + 16 * nf] = __float2bfloat16(p);
                    }
                }
            } else {
                #pragma unroll
                for (int nf = 0; nf < 4; ++nf)
                    #pragma unroll
                    for (int r = 0; r < 4; ++r) {
                        float p = exp2_fast(s[nf][r]);
                        lsum[r] += p;
                        Ps[wid][(lane >> 4) * 4 + r][fr + 16 * nf] = __float2bfloat16(p);
                    }
            }

            // ---- O += P V ----
            short8 pa0 = *reinterpret_cast<const short8*>(&Ps[wid][fr][kf]);
            short8 pa1 = *reinterpret_cast<const short8*>(&Ps[wid][fr][32 + kf]);
            #pragma unroll
            for (int nf = 0; nf < 4; ++nf) {
                short8 b0 = *reinterpret_cast<const short8*>(&Vs[fr + 16 * nf][kf]);
                short8 b1 = *reinterpret_cast<const short8*>(&Vs[fr + 16 * nf][32 + kf]);
                o[nf] = __builtin_amdgcn_mfma_f32_16x16x32_bf16(pa0, b0, o[nf], 0, 0, 0);
                o[nf] = __builtin_amdgcn_mfma_f32_16x16x32_bf16(pa1, b1, o[nf], 0, 0, 0);
            }
            __syncthreads();   // all waves done reading Ks/Vs

            if (more) {
                *reinterpret_cast<short8*>(&Ks[sr0][sc0]) = nk0;
                *reinterpret_cast<short8*>(&Ks[sr1][sc1]) = nk1;
                *reinterpret_cast<short8*>(&Vs[sr0][sc0]) = nv0;
                *reinterpret_cast<short8*>(&Vs[sr1][sc1]) = nv1;
                __syncthreads();   // next tile ready
            }
        }

        // ---- single deferred row-sum reduce + epilogue ----
        float linv[4];
        #pragma unroll
        for (int r = 0; r < 4; ++r) {
            float v = lsum[r];
            v += __shfl_xor(v, 1, 64);
            v += __shfl_xor(v, 2, 64);
            v += __shfl_xor(v, 4, 64);
            v += __shfl_xor(v, 8, 64);
            linv[r] = 1.0f / v;
        }
        #pragma unroll
        for (int nf = 0; nf < 4; ++nf) {
            int col = fr + 16 * nf;
            #pragma unroll
            for (int r = 0; r < 4; ++r) {
                float v = o[nf][r] * linv[r];
                out[((size_t)(b * T_ + rbase + r)) * (H_ * HD_) + h * HD_ + col] =
                    __float2bfloat16(v);
            }
        }
    }
}

extern "C" void kernel_launch(void* const* d_in, const int* in_sizes, int n_in,
                              void* d_out, int out_size, void* d_ws, size_t ws_size,
                              hipStream_t stream) {
    const float* x_f     = (const float*)d_in[0];   // [8192,1024]
    const float* w_qkv_f = (const float*)d_in[1];   // [1024,1536]
    const float* w_o_f   = (const float*)d_in[2];   // [1024,1024]
    float* out = (float*)d_out;

    const int NX  = B_ * T_ * D_;
    const int NWQ = D_ * QKVW;
    const int NWO = D_ * D_;

    __hip_bfloat16* xb    = (__hip_bfloat16*)d_ws;
    __hip_bfloat16* wqkvT = xb + NX;
    __hip_bfloat16* woT   = wqkvT + NWQ;
    __hip_bfloat16* qkv   = woT + NWO;
    __hip_bfloat16* vt    = qkv + (size_t)(B_ * T_) * QKVW;
    __hip_bfloat16* attn_out = xb;   // alias: xb dead after gemm1

    dim3 blk(256);

    cvt_f32_bf16<<<dim3(NX / 2048), blk, 0, stream>>>(x_f, xb, NX);
    cvt_transpose<<<dim3(QKVW / 32, D_ / 32), blk, 0, stream>>>(w_qkv_f, wqkvT, D_, QKVW);
    cvt_transpose<<<dim3(D_ / 32, D_ / 32), blk, 0, stream>>>(w_o_f, woT, D_, D_);

    // 1) qkv = x @ w_qkv  (grid = 12*64 = 768, %8==0)
    gemm_tn<__hip_bfloat16><<<dim3((QKVW / 128) * ((B_ * T_) / 128)), blk, 0, stream>>>(
        xb, wqkvT, qkv, B_ * T_, QKVW, D_);

    // 2) l2norm (vectorized; folds 0.125*log2e into q)
    l2norm_qk<<<dim3((B_ * T_ * H_ + B_ * T_ * G_) / 32), blk, 0, stream>>>(qkv);

    vt_build<<<dim3(T_ / 32, HD_ / 32, B_ * G_), blk, 0, stream>>>(qkv, vt);

    attn_fwd<<<dim3(8, H_, B_), blk, 0, stream>>>(qkv, vt, attn_out);

    // 5) out = attn_out @ w_o  (grid = 8*64 = 512, %8==0)
    gemm_tn<float><<<dim3((D_ / 128) * ((B_ * T_) / 128)), blk, 0, stream>>>(
        attn_out, woT, out, B_ * T_, D_, D_);
}

// Round 7
// 133.977 us; speedup vs baseline: 2.8349x; 1.0197x over previous
//
#include <hip/hip_runtime.h>
#include <hip/hip_bf16.h>

typedef __attribute__((ext_vector_type(8))) short short8;
typedef __attribute__((ext_vector_type(4))) float f32x4;

#define B_ 8
#define T_ 1024
#define D_ 1024
#define H_ 16
#define G_ 4
#define HD_ 64
#define QKVW 1536   // H*HD + 2*G*HD

#define GLOAD16(gp, lp) __builtin_amdgcn_global_load_lds( \
    (const __attribute__((address_space(1))) void*)(gp),  \
    (__attribute__((address_space(3))) void*)(lp), 16, 0, 0)

// fast 2^x on gfx950 (v_exp_f32)
__device__ __forceinline__ float exp2_fast(float x) {
    return __builtin_amdgcn_exp2f(x);
}

// ---------------------------------------------------------------------------
// fp32 -> bf16 conversion, 8 elems/thread.
// ---------------------------------------------------------------------------
__global__ __launch_bounds__(256) void cvt_f32_bf16(
    const float* __restrict__ in, __hip_bfloat16* __restrict__ out, int n)
{
    int i = (blockIdx.x * 256 + threadIdx.x) * 8;
    if (i >= n) return;
    float4 a = *reinterpret_cast<const float4*>(in + i);
    float4 b = *reinterpret_cast<const float4*>(in + i + 4);
    union { short8 s; __hip_bfloat16 h[8]; } u;
    u.h[0] = __float2bfloat16(a.x); u.h[1] = __float2bfloat16(a.y);
    u.h[2] = __float2bfloat16(a.z); u.h[3] = __float2bfloat16(a.w);
    u.h[4] = __float2bfloat16(b.x); u.h[5] = __float2bfloat16(b.y);
    u.h[6] = __float2bfloat16(b.z); u.h[7] = __float2bfloat16(b.w);
    *reinterpret_cast<short8*>(out + i) = u.s;
}

// ---------------------------------------------------------------------------
// fp32 [K][N] -> bf16 transposed [N][K], LDS-tiled 32x32.
// ---------------------------------------------------------------------------
__global__ __launch_bounds__(256) void cvt_transpose(
    const float* __restrict__ in, __hip_bfloat16* __restrict__ outT, int K, int N)
{
    __shared__ float tile[32][33];
    const int k0 = blockIdx.y * 32, n0 = blockIdx.x * 32;
    const int r = threadIdx.x >> 5, c = threadIdx.x & 31;
    #pragma unroll
    for (int i = 0; i < 4; ++i)
        tile[r + i * 8][c] = in[(size_t)(k0 + r + i * 8) * N + n0 + c];
    __syncthreads();
    #pragma unroll
    for (int i = 0; i < 4; ++i)
        outT[(size_t)(n0 + r + i * 8) * K + k0 + c] = __float2bfloat16(tile[c][r + i * 8]);
}

// ---------------------------------------------------------------------------
// GEMM: C[M][N] = A[M][K] * Bt[N][K]^T. 128x128 tile, BK=32, 4 waves,
// global_load_lds width=16, 2-phase LDS double-buffer, XCD band swizzle.
// ---------------------------------------------------------------------------
template <typename CT>
__global__ __launch_bounds__(256) void gemm_tn(
    const __hip_bfloat16* __restrict__ A,
    const __hip_bfloat16* __restrict__ Bt,
    CT* __restrict__ C, int M, int N, int K)
{
    __shared__ __hip_bfloat16 As[2][128 * 32];
    __shared__ __hip_bfloat16 Bs[2][128 * 32];

    const int tid  = threadIdx.x;
    const int lane = tid & 63;
    const int wr   = (tid >> 6) >> 1;
    const int wc   = (tid >> 6) & 1;

    const int NBY = M >> 7;
    const int rpx = NBY >> 3;
    const int xcd = blockIdx.x & 7;
    const int lin = blockIdx.x >> 3;
    const int by  = xcd * rpx + (lin % rpx);
    const int bx  = lin / rpx;
    const int m0 = by * 128;
    const int n0 = bx * 128;

    f32x4 acc[4][4] = {};

    const int s0 = tid * 8,          sr0 = s0 >> 5, sc0 = s0 & 31;
    const int s1 = (256 + tid) * 8,  sr1 = s1 >> 5, sc1 = s1 & 31;

    const __hip_bfloat16* Ar0 = A  + (size_t)(m0 + sr0) * K + sc0;
    const __hip_bfloat16* Ar1 = A  + (size_t)(m0 + sr1) * K + sc1;
    const __hip_bfloat16* Br0 = Bt + (size_t)(n0 + sr0) * K + sc0;
    const __hip_bfloat16* Br1 = Bt + (size_t)(n0 + sr1) * K + sc1;

    const int fr = lane & 15;
    const int kf = (lane >> 4) * 8;

    GLOAD16(Ar0, &As[0][s0]);
    GLOAD16(Ar1, &As[0][s1]);
    GLOAD16(Br0, &Bs[0][s0]);
    GLOAD16(Br1, &Bs[0][s1]);
    __syncthreads();

    int cur = 0;
    for (int kk = 0; kk < K; kk += 32) {
        const int nxt = cur ^ 1;
        if (kk + 32 < K) {
            GLOAD16(Ar0 + kk + 32, &As[nxt][s0]);
            GLOAD16(Ar1 + kk + 32, &As[nxt][s1]);
            GLOAD16(Br0 + kk + 32, &Bs[nxt][s0]);
            GLOAD16(Br1 + kk + 32, &Bs[nxt][s1]);
        }
        short8 a[4], b[4];
        #pragma unroll
        for (int m = 0; m < 4; ++m)
            a[m] = *reinterpret_cast<const short8*>(&As[cur][(wr * 64 + m * 16 + fr) * 32 + kf]);
        #pragma unroll
        for (int n = 0; n < 4; ++n)
            b[n] = *reinterpret_cast<const short8*>(&Bs[cur][(wc * 64 + n * 16 + fr) * 32 + kf]);
        #pragma unroll
        for (int m = 0; m < 4; ++m)
            #pragma unroll
            for (int n = 0; n < 4; ++n)
                acc[m][n] = __builtin_amdgcn_mfma_f32_16x16x32_bf16(a[m], b[n], acc[m][n], 0, 0, 0);
        __syncthreads();
        cur = nxt;
    }

    const int rowb = m0 + wr * 64 + (lane >> 4) * 4;
    const int colb = n0 + wc * 64 + fr;
    #pragma unroll
    for (int m = 0; m < 4; ++m)
        #pragma unroll
        for (int n = 0; n < 4; ++n)
            #pragma unroll
            for (int r = 0; r < 4; ++r) {
                float v = acc[m][n][r];
                if constexpr (__is_same(CT, float))
                    C[(size_t)(rowb + m * 16 + r) * N + colb + n * 16] = v;
                else
                    C[(size_t)(rowb + m * 16 + r) * N + colb + n * 16] = __float2bfloat16(v);
            }
}

// ---------------------------------------------------------------------------
// L2-normalize q,k in-place, vectorized; folds 0.125*log2(e) into q.
// ---------------------------------------------------------------------------
__global__ __launch_bounds__(256) void l2norm_qk(__hip_bfloat16* __restrict__ qkv)
{
    const int tid = threadIdx.x;
    const int vec = blockIdx.x * 32 + (tid >> 3);
    const int j   = tid & 7;
    const int NQ  = B_ * T_ * H_;

    size_t base;
    float extra;
    if (vec < NQ) {
        int bt = vec >> 4, h = vec & 15;
        base = (size_t)bt * QKVW + h * HD_;
        extra = 0.125f * 1.44269504f;
    } else {
        int v = vec - NQ;
        int bt = v >> 2, g = v & 3;
        base = (size_t)bt * QKVW + H_ * HD_ + g * HD_;
        extra = 1.0f;
    }

    union { short8 s; __hip_bfloat16 h[8]; } u;
    u.s = *reinterpret_cast<const short8*>(qkv + base + j * 8);
    float f[8], ss = 0.f;
    #pragma unroll
    for (int i = 0; i < 8; ++i) { f[i] = __bfloat162float(u.h[i]); ss += f[i] * f[i]; }
    ss += __shfl_xor(ss, 1, 64);
    ss += __shfl_xor(ss, 2, 64);
    ss += __shfl_xor(ss, 4, 64);
    float sc = extra / (sqrtf(ss) + 1e-10f);
    #pragma unroll
    for (int i = 0; i < 8; ++i) u.h[i] = __float2bfloat16(f[i] * sc);
    *reinterpret_cast<short8*>(qkv + base + j * 8) = u.s;
}

// ---------------------------------------------------------------------------
// Build transposed V: vt[(b*G+g)*64 + d][t] = v[b][t][g][d].
// ---------------------------------------------------------------------------
__global__ __launch_bounds__(256) void vt_build(
    const __hip_bfloat16* __restrict__ qkv, __hip_bfloat16* __restrict__ vt)
{
    __shared__ __hip_bfloat16 tile[32][33];
    const int t0 = blockIdx.x * 32;
    const int d0 = blockIdx.y * 32;
    const int bg = blockIdx.z;
    const int r = threadIdx.x >> 5, c = threadIdx.x & 31;
    #pragma unroll
    for (int i = 0; i < 4; ++i)
        tile[r + i * 8][c] = qkv[((size_t)((bg >> 2) * T_ + t0 + r + i * 8)) * QKVW
                                 + (H_ + G_) * HD_ + (bg & 3) * HD_ + d0 + c];
    __syncthreads();
    #pragma unroll
    for (int i = 0; i < 4; ++i)
        vt[((size_t)(bg * HD_ + d0 + r + i * 8)) * T_ + t0 + c] = tile[c][r + i * 8];
}

// ---------------------------------------------------------------------------
// Flash attention, causal, GQA. Degenerate softmax (L2-normed q,k; scale
// folded into q): p = exp2(s), deferred row-sum. Dense [64][64] LDS tiles
// with XOR-16B swizzle; staged via global_load_lds with PRE-SWIZZLED global
// source (linear LDS dest + swizzled reads = consistent involution).
// ---------------------------------------------------------------------------
__global__ __launch_bounds__(256) void attn_fwd(
    const __hip_bfloat16* __restrict__ qkv,
    const __hip_bfloat16* __restrict__ vt,
    __hip_bfloat16* __restrict__ out)   // [B,T,H*HD]
{
    const int pair = blockIdx.x;        // 0..7
    const int h  = blockIdx.y;
    const int b  = blockIdx.z;
    const int g  = h >> 2;

    const int tid  = threadIdx.x;
    const int lane = tid & 63;
    const int wid  = tid >> 6;

    __shared__ __hip_bfloat16 Ks[64 * 64];
    __shared__ __hip_bfloat16 Vs[64 * 64];
    __shared__ __hip_bfloat16 Ps[4 * 16 * 64];

    const int fr  = lane & 15;
    const int kf  = (lane >> 4) * 8;       // elem col base
    const int kb  = kf * 2;                // byte col base {0,16,32,48}
    const int swz = (fr & 7) << 4;         // read-swizzle constant (bytes)

    // staging: lane covers LDS row srow (and srow+32), 8 elems; global col
    // pre-swizzled so that swizzled reads recover the identity mapping.
    const int srow = tid >> 3;                              // 0..31
    const int scol = ((tid & 7) * 8) ^ ((srow & 7) << 3);   // elems

    const size_t kgbase = (size_t)(b * T_) * QKVW + H_ * HD_ + g * HD_ + scol;
    const size_t vgbase = (size_t)((b * G_ + g) * HD_) * T_ + scol;

    char* KsB = (char*)Ks;
    char* VsB = (char*)Vs;
    char* PsB = (char*)Ps + wid * 2048;    // 16*64*2 bytes per wave

    for (int half = 0; half < 2; ++half) {
        const int qt = half ? (15 - pair) : pair;
        const int q0 = qt * 64;
        const int arow  = q0 + wid * 16 + fr;
        const int rbase = q0 + wid * 16 + (lane >> 4) * 4;

        short8 qfrag0, qfrag1;
        {
            const size_t qbase = ((size_t)(b * T_ + arow)) * QKVW + h * HD_;
            qfrag0 = *reinterpret_cast<const short8*>(qkv + qbase + kf);
            qfrag1 = *reinterpret_cast<const short8*>(qkv + qbase + 32 + kf);
        }

        float lsum[4] = {0.f, 0.f, 0.f, 0.f};
        f32x4 o[4] = {};

        for (int kt = 0; kt <= qt; ++kt) {
            const bool diag = (kt == qt);

            // ---- stage K,V tiles: global_load_lds, pre-swizzled source ----
            GLOAD16(qkv + kgbase + (size_t)(kt * 64 + srow) * QKVW,      &Ks[tid * 8]);
            GLOAD16(qkv + kgbase + (size_t)(kt * 64 + 32 + srow) * QKVW, &Ks[2048 + tid * 8]);
            GLOAD16(vt + vgbase + (size_t)srow * T_ + kt * 64,           &Vs[tid * 8]);
            GLOAD16(vt + vgbase + (size_t)(32 + srow) * T_ + kt * 64,    &Vs[2048 + tid * 8]);
            __syncthreads();

            // ---- S = Q K^T ----
            f32x4 s[4] = {};
            #pragma unroll
            for (int nf = 0; nf < 4; ++nf) {
                const int row = fr + 16 * nf;
                short8 b0 = *reinterpret_cast<const short8*>(KsB + row * 128 + (kb ^ swz));
                short8 b1 = *reinterpret_cast<const short8*>(KsB + row * 128 + ((64 + kb) ^ swz));
                s[nf] = __builtin_amdgcn_mfma_f32_16x16x32_bf16(qfrag0, b0, s[nf], 0, 0, 0);
                s[nf] = __builtin_amdgcn_mfma_f32_16x16x32_bf16(qfrag1, b1, s[nf], 0, 0, 0);
            }

            // ---- p = exp2(s); write P (swizzled), accumulate row-sum ----
            if (diag) {
                #pragma unroll
                for (int nf = 0; nf < 4; ++nf) {
                    int col = kt * 64 + fr + 16 * nf;
                    #pragma unroll
                    for (int r = 0; r < 4; ++r) {
                        float p = (col <= rbase + r) ? exp2_fast(s[nf][r]) : 0.f;
                        lsum[r] += p;
                        int q = (lane >> 4) * 4 + r;
                        *(__hip_bfloat16*)(PsB + q * 128 +
                            ((2 * (fr + 16 * nf)) ^ ((q & 7) << 4))) = __float2bfloat16(p);
                    }
                }
            } else {
                #pragma unroll
                for (int nf = 0; nf < 4; ++nf)
                    #pragma unroll
                    for (int r = 0; r < 4; ++r) {
                        float p = exp2_fast(s[nf][r]);
                        lsum[r] += p;
                        int q = (lane >> 4) * 4 + r;
                        *(__hip_bfloat16*)(PsB + q * 128 +
                            ((2 * (fr + 16 * nf)) ^ ((q & 7) << 4))) = __float2bfloat16(p);
                    }
            }

            // ---- O += P V ----
            short8 pa0 = *reinterpret_cast<const short8*>(PsB + fr * 128 + (kb ^ swz));
            short8 pa1 = *reinterpret_cast<const short8*>(PsB + fr * 128 + ((64 + kb) ^ swz));
            #pragma unroll
            for (int nf = 0; nf < 4; ++nf) {
                const int row = fr + 16 * nf;
                short8 b0 = *reinterpret_cast<const short8*>(VsB + row * 128 + (kb ^ swz));
                short8 b1 = *reinterpret_cast<const short8*>(VsB + row * 128 + ((64 + kb) ^ swz));
                o[nf] = __builtin_amdgcn_mfma_f32_16x16x32_bf16(pa0, b0, o[nf], 0, 0, 0);
                o[nf] = __builtin_amdgcn_mfma_f32_16x16x32_bf16(pa1, b1, o[nf], 0, 0, 0);
            }
            __syncthreads();
        }

        // ---- deferred row-sum reduce + epilogue ----
        float linv[4];
        #pragma unroll
        for (int r = 0; r < 4; ++r) {
            float v = lsum[r];
            v += __shfl_xor(v, 1, 64);
            v += __shfl_xor(v, 2, 64);
            v += __shfl_xor(v, 4, 64);
            v += __shfl_xor(v, 8, 64);
            linv[r] = 1.0f / v;
        }
        #pragma unroll
        for (int nf = 0; nf < 4; ++nf) {
            int col = fr + 16 * nf;
            #pragma unroll
            for (int r = 0; r < 4; ++r) {
                float v = o[nf][r] * linv[r];
                out[((size_t)(b * T_ + rbase + r)) * (H_ * HD_) + h * HD_ + col] =
                    __float2bfloat16(v);
            }
        }
    }
}

extern "C" void kernel_launch(void* const* d_in, const int* in_sizes, int n_in,
                              void* d_out, int out_size, void* d_ws, size_t ws_size,
                              hipStream_t stream) {
    const float* x_f     = (const float*)d_in[0];   // [8192,1024]
    const float* w_qkv_f = (const float*)d_in[1];   // [1024,1536]
    const float* w_o_f   = (const float*)d_in[2];   // [1024,1024]
    float* out = (float*)d_out;

    const int NX  = B_ * T_ * D_;
    const int NWQ = D_ * QKVW;
    const int NWO = D_ * D_;

    __hip_bfloat16* xb    = (__hip_bfloat16*)d_ws;
    __hip_bfloat16* wqkvT = xb + NX;
    __hip_bfloat16* woT   = wqkvT + NWQ;
    __hip_bfloat16* qkv   = woT + NWO;
    __hip_bfloat16* vt    = qkv + (size_t)(B_ * T_) * QKVW;
    __hip_bfloat16* attn_out = xb;   // alias: xb dead after gemm1

    dim3 blk(256);

    cvt_f32_bf16<<<dim3(NX / 2048), blk, 0, stream>>>(x_f, xb, NX);
    cvt_transpose<<<dim3(QKVW / 32, D_ / 32), blk, 0, stream>>>(w_qkv_f, wqkvT, D_, QKVW);
    cvt_transpose<<<dim3(D_ / 32, D_ / 32), blk, 0, stream>>>(w_o_f, woT, D_, D_);

    // 1) qkv = x @ w_qkv  (grid = 12*64 = 768, %8==0)
    gemm_tn<__hip_bfloat16><<<dim3((QKVW / 128) * ((B_ * T_) / 128)), blk, 0, stream>>>(
        xb, wqkvT, qkv, B_ * T_, QKVW, D_);

    l2norm_qk<<<dim3((B_ * T_ * H_ + B_ * T_ * G_) / 32), blk, 0, stream>>>(qkv);

    vt_build<<<dim3(T_ / 32, HD_ / 32, B_ * G_), blk, 0, stream>>>(qkv, vt);

    attn_fwd<<<dim3(8, H_, B_), blk, 0, stream>>>(qkv, vt, attn_out);

    // 5) out = attn_out @ w_o  (grid = 8*64 = 512, %8==0)
    gemm_tn<float><<<dim3((D_ / 128) * ((B_ * T_) / 128)), blk, 0, stream>>>(
        attn_out, woT, out, B_ * T_, D_, D_);
}

// Round 8
// 130.323 us; speedup vs baseline: 2.9143x; 1.0280x over previous
//
#include <hip/hip_runtime.h>
#include <hip/hip_bf16.h>

typedef __attribute__((ext_vector_type(8))) short short8;
typedef __attribute__((ext_vector_type(4))) short short4v;
typedef __attribute__((ext_vector_type(4))) float f32x4;

#define B_ 8
#define T_ 1024
#define D_ 1024
#define H_ 16
#define G_ 4
#define HD_ 64
#define QKVW 1536   // 1024 q | 256 k | 256 v

#define GLOAD16(gp, lp) __builtin_amdgcn_global_load_lds( \
    (const __attribute__((address_space(1))) void*)(gp),  \
    (__attribute__((address_space(3))) void*)(lp), 16, 0, 0)

__device__ __forceinline__ float exp2_fast(float x) {
    return __builtin_amdgcn_exp2f(x);
}

// ---------------------------------------------------------------------------
// fp32 -> bf16 conversion, 8 elems/thread.
// ---------------------------------------------------------------------------
__global__ __launch_bounds__(256) void cvt_f32_bf16(
    const float* __restrict__ in, __hip_bfloat16* __restrict__ out, int n)
{
    int i = (blockIdx.x * 256 + threadIdx.x) * 8;
    if (i >= n) return;
    float4 a = *reinterpret_cast<const float4*>(in + i);
    float4 b = *reinterpret_cast<const float4*>(in + i + 4);
    union { short8 s; __hip_bfloat16 h[8]; } u;
    u.h[0] = __float2bfloat16(a.x); u.h[1] = __float2bfloat16(a.y);
    u.h[2] = __float2bfloat16(a.z); u.h[3] = __float2bfloat16(a.w);
    u.h[4] = __float2bfloat16(b.x); u.h[5] = __float2bfloat16(b.y);
    u.h[6] = __float2bfloat16(b.z); u.h[7] = __float2bfloat16(b.w);
    *reinterpret_cast<short8*>(out + i) = u.s;
}

// ---------------------------------------------------------------------------
// fp32 [K][N] -> bf16 transposed [N][K], LDS-tiled 32x32.
// ---------------------------------------------------------------------------
__global__ __launch_bounds__(256) void cvt_transpose(
    const float* __restrict__ in, __hip_bfloat16* __restrict__ outT, int K, int N)
{
    __shared__ float tile[32][33];
    const int k0 = blockIdx.y * 32, n0 = blockIdx.x * 32;
    const int r = threadIdx.x >> 5, c = threadIdx.x & 31;
    #pragma unroll
    for (int i = 0; i < 4; ++i)
        tile[r + i * 8][c] = in[(size_t)(k0 + r + i * 8) * N + n0 + c];
    __syncthreads();
    #pragma unroll
    for (int i = 0; i < 4; ++i)
        outT[(size_t)(n0 + r + i * 8) * K + k0 + c] = __float2bfloat16(tile[c][r + i * 8]);
}

// ---------------------------------------------------------------------------
// Fused QKV GEMM: qkv_part = x @ w_qkvT^T with fused epilogue:
//   q cols (<1024):  L2-normalize over head + fold 0.125*log2e, write qkv
//   k cols (1024..1279): L2-normalize, write qkv
//   v cols (>=1280): write TRANSPOSED to vt[(b*G+g)*64+d][t]  (skip qkv)
// 128x128 tile, BK=32, dbuf, global_load_lds, XCD band swizzle.
// ---------------------------------------------------------------------------
__global__ __launch_bounds__(256) void gemm_qkv(
    const __hip_bfloat16* __restrict__ A,
    const __hip_bfloat16* __restrict__ Bt,
    __hip_bfloat16* __restrict__ qkv,
    __hip_bfloat16* __restrict__ vt)
{
    const int M = B_ * T_, K = D_;
    __shared__ __hip_bfloat16 As[2][128 * 32];
    __shared__ __hip_bfloat16 Bs[2][128 * 32];

    const int tid  = threadIdx.x;
    const int lane = tid & 63;
    const int wr   = (tid >> 6) >> 1;
    const int wc   = (tid >> 6) & 1;

    const int rpx = (M >> 7) >> 3;          // 8
    const int xcd = blockIdx.x & 7;
    const int lin = blockIdx.x >> 3;
    const int by  = xcd * rpx + (lin % rpx);
    const int bx  = lin / rpx;
    const int m0 = by * 128;
    const int n0 = bx * 128;

    f32x4 acc[4][4] = {};

    const int s0 = tid * 8,          sr0 = s0 >> 5, sc0 = s0 & 31;
    const int s1 = (256 + tid) * 8,  sr1 = s1 >> 5, sc1 = s1 & 31;

    const __hip_bfloat16* Ar0 = A  + (size_t)(m0 + sr0) * K + sc0;
    const __hip_bfloat16* Ar1 = A  + (size_t)(m0 + sr1) * K + sc1;
    const __hip_bfloat16* Br0 = Bt + (size_t)(n0 + sr0) * K + sc0;
    const __hip_bfloat16* Br1 = Bt + (size_t)(n0 + sr1) * K + sc1;

    const int fr = lane & 15;
    const int kf = (lane >> 4) * 8;

    GLOAD16(Ar0, &As[0][s0]);
    GLOAD16(Ar1, &As[0][s1]);
    GLOAD16(Br0, &Bs[0][s0]);
    GLOAD16(Br1, &Bs[0][s1]);
    __syncthreads();

    int cur = 0;
    for (int kk = 0; kk < K; kk += 32) {
        const int nxt = cur ^ 1;
        if (kk + 32 < K) {
            GLOAD16(Ar0 + kk + 32, &As[nxt][s0]);
            GLOAD16(Ar1 + kk + 32, &As[nxt][s1]);
            GLOAD16(Br0 + kk + 32, &Bs[nxt][s0]);
            GLOAD16(Br1 + kk + 32, &Bs[nxt][s1]);
        }
        short8 a[4], b[4];
        #pragma unroll
        for (int m = 0; m < 4; ++m)
            a[m] = *reinterpret_cast<const short8*>(&As[cur][(wr * 64 + m * 16 + fr) * 32 + kf]);
        #pragma unroll
        for (int n = 0; n < 4; ++n)
            b[n] = *reinterpret_cast<const short8*>(&Bs[cur][(wc * 64 + n * 16 + fr) * 32 + kf]);
        #pragma unroll
        for (int m = 0; m < 4; ++m)
            #pragma unroll
            for (int n = 0; n < 4; ++n)
                acc[m][n] = __builtin_amdgcn_mfma_f32_16x16x32_bf16(a[m], b[n], acc[m][n], 0, 0, 0);
        __syncthreads();
        cur = nxt;
    }

    const int rowb  = m0 + wr * 64 + (lane >> 4) * 4;
    const int colb0 = n0 + wc * 64;          // head-aligned 64-col span

    if (n0 < 1280) {
        // q or k head: L2-normalize over the 64-dim head (4 vals/lane x 16 lanes)
        const float extra = (n0 < 1024) ? 0.18033688f : 1.0f;   // 0.125*log2(e) | 1
        #pragma unroll
        for (int m = 0; m < 4; ++m)
            #pragma unroll
            for (int r = 0; r < 4; ++r) {
                float ss = 0.f;
                #pragma unroll
                for (int n = 0; n < 4; ++n) { float v = acc[m][n][r]; ss += v * v; }
                ss += __shfl_xor(ss, 1, 64);
                ss += __shfl_xor(ss, 2, 64);
                ss += __shfl_xor(ss, 4, 64);
                ss += __shfl_xor(ss, 8, 64);
                float sc = extra / (sqrtf(ss) + 1e-10f);
                const size_t rbase = (size_t)(rowb + m * 16 + r) * QKVW + colb0 + fr;
                #pragma unroll
                for (int n = 0; n < 4; ++n)
                    qkv[rbase + n * 16] = __float2bfloat16(acc[m][n][r] * sc);
            }
    } else {
        // v: write transposed vt[(b*G+g)*64+d][t], 4 consecutive t per (m,n)
        #pragma unroll
        for (int m = 0; m < 4; ++m) {
            const int row = rowb + m * 16;
            const int b   = row >> 10;
            const int t0  = row & 1023;
            #pragma unroll
            for (int n = 0; n < 4; ++n) {
                const int cv = colb0 + fr + n * 16 - 1280;   // 0..255
                const int gg = cv >> 6, d = cv & 63;
                union { short4v s; __hip_bfloat16 h[4]; } u;
                u.h[0] = __float2bfloat16(acc[m][n][0]);
                u.h[1] = __float2bfloat16(acc[m][n][1]);
                u.h[2] = __float2bfloat16(acc[m][n][2]);
                u.h[3] = __float2bfloat16(acc[m][n][3]);
                *reinterpret_cast<short4v*>(
                    vt + ((size_t)((b * G_ + gg) * HD_ + d)) * T_ + t0) = u.s;
            }
        }
    }
}

// ---------------------------------------------------------------------------
// Plain GEMM for the output projection: C = A * Bt^T -> fp32.
// ---------------------------------------------------------------------------
__global__ __launch_bounds__(256) void gemm_tn_f32(
    const __hip_bfloat16* __restrict__ A,
    const __hip_bfloat16* __restrict__ Bt,
    float* __restrict__ C, int M, int N, int K)
{
    __shared__ __hip_bfloat16 As[2][128 * 32];
    __shared__ __hip_bfloat16 Bs[2][128 * 32];

    const int tid  = threadIdx.x;
    const int lane = tid & 63;
    const int wr   = (tid >> 6) >> 1;
    const int wc   = (tid >> 6) & 1;

    const int rpx = (M >> 7) >> 3;
    const int xcd = blockIdx.x & 7;
    const int lin = blockIdx.x >> 3;
    const int by  = xcd * rpx + (lin % rpx);
    const int bx  = lin / rpx;
    const int m0 = by * 128;
    const int n0 = bx * 128;

    f32x4 acc[4][4] = {};

    const int s0 = tid * 8,          sr0 = s0 >> 5, sc0 = s0 & 31;
    const int s1 = (256 + tid) * 8,  sr1 = s1 >> 5, sc1 = s1 & 31;

    const __hip_bfloat16* Ar0 = A  + (size_t)(m0 + sr0) * K + sc0;
    const __hip_bfloat16* Ar1 = A  + (size_t)(m0 + sr1) * K + sc1;
    const __hip_bfloat16* Br0 = Bt + (size_t)(n0 + sr0) * K + sc0;
    const __hip_bfloat16* Br1 = Bt + (size_t)(n0 + sr1) * K + sc1;

    const int fr = lane & 15;
    const int kf = (lane >> 4) * 8;

    GLOAD16(Ar0, &As[0][s0]);
    GLOAD16(Ar1, &As[0][s1]);
    GLOAD16(Br0, &Bs[0][s0]);
    GLOAD16(Br1, &Bs[0][s1]);
    __syncthreads();

    int cur = 0;
    for (int kk = 0; kk < K; kk += 32) {
        const int nxt = cur ^ 1;
        if (kk + 32 < K) {
            GLOAD16(Ar0 + kk + 32, &As[nxt][s0]);
            GLOAD16(Ar1 + kk + 32, &As[nxt][s1]);
            GLOAD16(Br0 + kk + 32, &Bs[nxt][s0]);
            GLOAD16(Br1 + kk + 32, &Bs[nxt][s1]);
        }
        short8 a[4], b[4];
        #pragma unroll
        for (int m = 0; m < 4; ++m)
            a[m] = *reinterpret_cast<const short8*>(&As[cur][(wr * 64 + m * 16 + fr) * 32 + kf]);
        #pragma unroll
        for (int n = 0; n < 4; ++n)
            b[n] = *reinterpret_cast<const short8*>(&Bs[cur][(wc * 64 + n * 16 + fr) * 32 + kf]);
        #pragma unroll
        for (int m = 0; m < 4; ++m)
            #pragma unroll
            for (int n = 0; n < 4; ++n)
                acc[m][n] = __builtin_amdgcn_mfma_f32_16x16x32_bf16(a[m], b[n], acc[m][n], 0, 0, 0);
        __syncthreads();
        cur = nxt;
    }

    const int rowb = m0 + wr * 64 + (lane >> 4) * 4;
    const int colb = n0 + wc * 64 + fr;
    #pragma unroll
    for (int m = 0; m < 4; ++m)
        #pragma unroll
        for (int n = 0; n < 4; ++n)
            #pragma unroll
            for (int r = 0; r < 4; ++r)
                C[(size_t)(rowb + m * 16 + r) * N + colb + n * 16] = acc[m][n][r];
}

// ---------------------------------------------------------------------------
// Flash attention, causal, GQA. Degenerate softmax (p = exp2(s), scale
// pre-folded into q by gemm_qkv). Double-buffered K/V staging via
// global_load_lds with pre-swizzled source; ONE barrier per k-tile.
// ---------------------------------------------------------------------------
__global__ __launch_bounds__(256) void attn_fwd(
    const __hip_bfloat16* __restrict__ qkv,
    const __hip_bfloat16* __restrict__ vt,
    __hip_bfloat16* __restrict__ out)   // [B,T,H*HD]
{
    const int pair = blockIdx.x;        // 0..7
    const int h  = blockIdx.y;
    const int b  = blockIdx.z;
    const int g  = h >> 2;

    const int tid  = threadIdx.x;
    const int lane = tid & 63;
    const int wid  = tid >> 6;

    __shared__ __hip_bfloat16 Ks[2 * 4096];
    __shared__ __hip_bfloat16 Vs[2 * 4096];
    __shared__ __hip_bfloat16 Ps[4 * 16 * 64];

    const int fr  = lane & 15;
    const int kf  = (lane >> 4) * 8;       // elem col base
    const int kb  = kf * 2;                // byte col base
    const int swz = (fr & 7) << 4;         // read-swizzle (bytes)

    const int srow = tid >> 3;                              // 0..31
    const int scol = ((tid & 7) * 8) ^ ((srow & 7) << 3);   // pre-swizzled col

    const size_t kgbase = (size_t)(b * T_) * QKVW + H_ * HD_ + g * HD_ + scol;
    const size_t vgbase = (size_t)((b * G_ + g) * HD_) * T_ + scol;

    char* PsB = (char*)Ps + wid * 2048;

    for (int half = 0; half < 2; ++half) {
        const int qt = half ? (15 - pair) : pair;
        const int q0 = qt * 64;
        const int arow  = q0 + wid * 16 + fr;
        const int rbase = q0 + wid * 16 + (lane >> 4) * 4;

        short8 qfrag0, qfrag1;
        {
            const size_t qbase = ((size_t)(b * T_ + arow)) * QKVW + h * HD_;
            qfrag0 = *reinterpret_cast<const short8*>(qkv + qbase + kf);
            qfrag1 = *reinterpret_cast<const short8*>(qkv + qbase + 32 + kf);
        }

        float lsum[4] = {0.f, 0.f, 0.f, 0.f};
        f32x4 o[4] = {};

        // prologue: stage tile 0 into buf 0
        GLOAD16(qkv + kgbase + (size_t)srow * QKVW,        &Ks[tid * 8]);
        GLOAD16(qkv + kgbase + (size_t)(32 + srow) * QKVW, &Ks[2048 + tid * 8]);
        GLOAD16(vt + vgbase + (size_t)srow * T_,           &Vs[tid * 8]);
        GLOAD16(vt + vgbase + (size_t)(32 + srow) * T_,    &Vs[2048 + tid * 8]);
        __syncthreads();

        int cur = 0;
        for (int kt = 0; kt <= qt; ++kt) {
            const bool diag = (kt == qt);
            const int  nb   = (cur ^ 1) * 4096;

            // issue next tile's staging NOW (hides under compute; barrier drains)
            if (!diag) {
                GLOAD16(qkv + kgbase + (size_t)((kt + 1) * 64 + srow) * QKVW,      &Ks[nb + tid * 8]);
                GLOAD16(qkv + kgbase + (size_t)((kt + 1) * 64 + 32 + srow) * QKVW, &Ks[nb + 2048 + tid * 8]);
                GLOAD16(vt + vgbase + (size_t)srow * T_ + (kt + 1) * 64,           &Vs[nb + tid * 8]);
                GLOAD16(vt + vgbase + (size_t)(32 + srow) * T_ + (kt + 1) * 64,    &Vs[nb + 2048 + tid * 8]);
            }

            char* KsB = (char*)(Ks + cur * 4096);
            char* VsB = (char*)(Vs + cur * 4096);

            // ---- S = Q K^T ----
            f32x4 s[4] = {};
            #pragma unroll
            for (int nf = 0; nf < 4; ++nf) {
                const int row = fr + 16 * nf;
                short8 b0 = *reinterpret_cast<const short8*>(KsB + row * 128 + (kb ^ swz));
                short8 b1 = *reinterpret_cast<const short8*>(KsB + row * 128 + ((64 + kb) ^ swz));
                s[nf] = __builtin_amdgcn_mfma_f32_16x16x32_bf16(qfrag0, b0, s[nf], 0, 0, 0);
                s[nf] = __builtin_amdgcn_mfma_f32_16x16x32_bf16(qfrag1, b1, s[nf], 0, 0, 0);
            }

            // ---- p = exp2(s); write P swizzled; accumulate row-sum ----
            if (diag) {
                #pragma unroll
                for (int nf = 0; nf < 4; ++nf) {
                    int col = kt * 64 + fr + 16 * nf;
                    #pragma unroll
                    for (int r = 0; r < 4; ++r) {
                        float p = (col <= rbase + r) ? exp2_fast(s[nf][r]) : 0.f;
                        lsum[r] += p;
                        int q = (lane >> 4) * 4 + r;
                        *(__hip_bfloat16*)(PsB + q * 128 +
                            ((2 * (fr + 16 * nf)) ^ ((q & 7) << 4))) = __float2bfloat16(p);
                    }
                }
            } else {
                #pragma unroll
                for (int nf = 0; nf < 4; ++nf)
                    #pragma unroll
                    for (int r = 0; r < 4; ++r) {
                        float p = exp2_fast(s[nf][r]);
                        lsum[r] += p;
                        int q = (lane >> 4) * 4 + r;
                        *(__hip_bfloat16*)(PsB + q * 128 +
                            ((2 * (fr + 16 * nf)) ^ ((q & 7) << 4))) = __float2bfloat16(p);
                    }
            }

            // ---- O += P V ----
            short8 pa0 = *reinterpret_cast<const short8*>(PsB + fr * 128 + (kb ^ swz));
            short8 pa1 = *reinterpret_cast<const short8*>(PsB + fr * 128 + ((64 + kb) ^ swz));
            #pragma unroll
            for (int nf = 0; nf < 4; ++nf) {
                const int row = fr + 16 * nf;
                short8 b0 = *reinterpret_cast<const short8*>(VsB + row * 128 + (kb ^ swz));
                short8 b1 = *reinterpret_cast<const short8*>(VsB + row * 128 + ((64 + kb) ^ swz));
                o[nf] = __builtin_amdgcn_mfma_f32_16x16x32_bf16(pa0, b0, o[nf], 0, 0, 0);
                o[nf] = __builtin_amdgcn_mfma_f32_16x16x32_bf16(pa1, b1, o[nf], 0, 0, 0);
            }
            __syncthreads();   // drains next-tile vmcnt + protects P/K/V reuse
            cur ^= 1;
        }

        // ---- deferred row-sum reduce + epilogue ----
        float linv[4];
        #pragma unroll
        for (int r = 0; r < 4; ++r) {
            float v = lsum[r];
            v += __shfl_xor(v, 1, 64);
            v += __shfl_xor(v, 2, 64);
            v += __shfl_xor(v, 4, 64);
            v += __shfl_xor(v, 8, 64);
            linv[r] = 1.0f / v;
        }
        #pragma unroll
        for (int nf = 0; nf < 4; ++nf) {
            int col = fr + 16 * nf;
            #pragma unroll
            for (int r = 0; r < 4; ++r) {
                float v = o[nf][r] * linv[r];
                out[((size_t)(b * T_ + rbase + r)) * (H_ * HD_) + h * HD_ + col] =
                    __float2bfloat16(v);
            }
        }
    }
}

extern "C" void kernel_launch(void* const* d_in, const int* in_sizes, int n_in,
                              void* d_out, int out_size, void* d_ws, size_t ws_size,
                              hipStream_t stream) {
    const float* x_f     = (const float*)d_in[0];   // [8192,1024]
    const float* w_qkv_f = (const float*)d_in[1];   // [1024,1536]
    const float* w_o_f   = (const float*)d_in[2];   // [1024,1024]
    float* out = (float*)d_out;

    const int NX  = B_ * T_ * D_;
    const int NWQ = D_ * QKVW;
    const int NWO = D_ * D_;

    __hip_bfloat16* xb    = (__hip_bfloat16*)d_ws;
    __hip_bfloat16* wqkvT = xb + NX;
    __hip_bfloat16* woT   = wqkvT + NWQ;
    __hip_bfloat16* qkv   = woT + NWO;
    __hip_bfloat16* vt    = qkv + (size_t)(B_ * T_) * QKVW;
    __hip_bfloat16* attn_out = xb;   // alias: xb dead after gemm_qkv

    dim3 blk(256);

    cvt_f32_bf16<<<dim3(NX / 2048), blk, 0, stream>>>(x_f, xb, NX);
    cvt_transpose<<<dim3(QKVW / 32, D_ / 32), blk, 0, stream>>>(w_qkv_f, wqkvT, D_, QKVW);
    cvt_transpose<<<dim3(D_ / 32, D_ / 32), blk, 0, stream>>>(w_o_f, woT, D_, D_);

    // fused QKV GEMM + L2-norm + scale-fold + V-transpose  (grid 768, %8==0)
    gemm_qkv<<<dim3((QKVW / 128) * ((B_ * T_) / 128)), blk, 0, stream>>>(
        xb, wqkvT, qkv, vt);

    attn_fwd<<<dim3(8, H_, B_), blk, 0, stream>>>(qkv, vt, attn_out);

    // out = attn_out @ w_o  (grid 512, %8==0)
    gemm_tn_f32<<<dim3((D_ / 128) * ((B_ * T_) / 128)), blk, 0, stream>>>(
        attn_out, woT, out, B_ * T_, D_, D_);
}

// Round 9
// 129.942 us; speedup vs baseline: 2.9229x; 1.0029x over previous
//
#include <hip/hip_runtime.h>
#include <hip/hip_bf16.h>

typedef __attribute__((ext_vector_type(8))) short short8;
typedef __attribute__((ext_vector_type(4))) short short4v;
typedef __attribute__((ext_vector_type(4))) float f32x4;

#define B_ 8
#define T_ 1024
#define D_ 1024
#define H_ 16
#define G_ 4
#define HD_ 64
#define QKVW 1536   // 1024 q | 256 k | 256 v

#define GLOAD16(gp, lp) __builtin_amdgcn_global_load_lds( \
    (const __attribute__((address_space(1))) void*)(gp),  \
    (__attribute__((address_space(3))) void*)(lp), 16, 0, 0)

__device__ __forceinline__ float exp2_fast(float x) {
    return __builtin_amdgcn_exp2f(x);
}

__device__ __forceinline__ short8 pack_bf16x8(float4 a, float4 b) {
    union { short8 s; __hip_bfloat16 h[8]; } u;
    u.h[0] = __float2bfloat16(a.x); u.h[1] = __float2bfloat16(a.y);
    u.h[2] = __float2bfloat16(a.z); u.h[3] = __float2bfloat16(a.w);
    u.h[4] = __float2bfloat16(b.x); u.h[5] = __float2bfloat16(b.y);
    u.h[6] = __float2bfloat16(b.z); u.h[7] = __float2bfloat16(b.w);
    return u.s;
}

// ---------------------------------------------------------------------------
// fp32 [K][N] -> bf16 transposed [N][K], LDS-tiled 32x32.
// ---------------------------------------------------------------------------
__global__ __launch_bounds__(256) void cvt_transpose(
    const float* __restrict__ in, __hip_bfloat16* __restrict__ outT, int K, int N)
{
    __shared__ float tile[32][33];
    const int k0 = blockIdx.y * 32, n0 = blockIdx.x * 32;
    const int r = threadIdx.x >> 5, c = threadIdx.x & 31;
    #pragma unroll
    for (int i = 0; i < 4; ++i)
        tile[r + i * 8][c] = in[(size_t)(k0 + r + i * 8) * N + n0 + c];
    __syncthreads();
    #pragma unroll
    for (int i = 0; i < 4; ++i)
        outT[(size_t)(n0 + r + i * 8) * K + k0 + c] = __float2bfloat16(tile[c][r + i * 8]);
}

// ---------------------------------------------------------------------------
// Fused QKV GEMM with fp32 A input (cvt fused into A staging, reg-staged) and
// epilogue fusion: q cols L2-norm + scale-fold; k cols L2-norm; v cols written
// transposed to vt. 128x128 tile, BK=32, dbuf, XCD band swizzle.
// ---------------------------------------------------------------------------
__global__ __launch_bounds__(256) void gemm_qkv(
    const float* __restrict__ Af,
    const __hip_bfloat16* __restrict__ Bt,
    __hip_bfloat16* __restrict__ qkv,
    __hip_bfloat16* __restrict__ vt)
{
    const int M = B_ * T_, K = D_;
    __shared__ __hip_bfloat16 As[2][128 * 32];
    __shared__ __hip_bfloat16 Bs[2][128 * 32];

    const int tid  = threadIdx.x;
    const int lane = tid & 63;
    const int wr   = (tid >> 6) >> 1;
    const int wc   = (tid >> 6) & 1;

    const int rpx = (M >> 7) >> 3;          // 8
    const int xcd = blockIdx.x & 7;
    const int lin = blockIdx.x >> 3;
    const int by  = xcd * rpx + (lin % rpx);
    const int bx  = lin / rpx;
    const int m0 = by * 128;
    const int n0 = bx * 128;

    f32x4 acc[4][4] = {};

    const int s0 = tid * 8,          sr0 = s0 >> 5, sc0 = s0 & 31;
    const int s1 = (256 + tid) * 8,  sr1 = s1 >> 5, sc1 = s1 & 31;

    const float* Ar0f = Af + (size_t)(m0 + sr0) * K + sc0;
    const float* Ar1f = Af + (size_t)(m0 + sr1) * K + sc1;
    const __hip_bfloat16* Br0 = Bt + (size_t)(n0 + sr0) * K + sc0;
    const __hip_bfloat16* Br1 = Bt + (size_t)(n0 + sr1) * K + sc1;

    const int fr = lane & 15;
    const int kf = (lane >> 4) * 8;

    // prologue
    float4 a0a = *(const float4*)(Ar0f);
    float4 a0b = *(const float4*)(Ar0f + 4);
    float4 a1a = *(const float4*)(Ar1f);
    float4 a1b = *(const float4*)(Ar1f + 4);
    GLOAD16(Br0, &Bs[0][s0]);
    GLOAD16(Br1, &Bs[0][s1]);
    *(short8*)&As[0][s0] = pack_bf16x8(a0a, a0b);
    *(short8*)&As[0][s1] = pack_bf16x8(a1a, a1b);
    __syncthreads();

    int cur = 0;
    for (int kk = 0; kk < K; kk += 32) {
        const int nxt = cur ^ 1;
        const bool more = (kk + 32 < K);
        if (more) {
            a0a = *(const float4*)(Ar0f + kk + 32);
            a0b = *(const float4*)(Ar0f + kk + 36);
            a1a = *(const float4*)(Ar1f + kk + 32);
            a1b = *(const float4*)(Ar1f + kk + 36);
            GLOAD16(Br0 + kk + 32, &Bs[nxt][s0]);
            GLOAD16(Br1 + kk + 32, &Bs[nxt][s1]);
        }
        short8 a[4], b[4];
        #pragma unroll
        for (int m = 0; m < 4; ++m)
            a[m] = *(const short8*)(&As[cur][(wr * 64 + m * 16 + fr) * 32 + kf]);
        #pragma unroll
        for (int n = 0; n < 4; ++n)
            b[n] = *(const short8*)(&Bs[cur][(wc * 64 + n * 16 + fr) * 32 + kf]);
        #pragma unroll
        for (int m = 0; m < 4; ++m)
            #pragma unroll
            for (int n = 0; n < 4; ++n)
                acc[m][n] = __builtin_amdgcn_mfma_f32_16x16x32_bf16(a[m], b[n], acc[m][n], 0, 0, 0);
        if (more) {
            *(short8*)&As[nxt][s0] = pack_bf16x8(a0a, a0b);
            *(short8*)&As[nxt][s1] = pack_bf16x8(a1a, a1b);
        }
        __syncthreads();
        cur = nxt;
    }

    const int rowb  = m0 + wr * 64 + (lane >> 4) * 4;
    const int colb0 = n0 + wc * 64;

    if (n0 < 1280) {
        const float extra = (n0 < 1024) ? 0.18033688f : 1.0f;   // 0.125*log2(e) | 1
        #pragma unroll
        for (int m = 0; m < 4; ++m)
            #pragma unroll
            for (int r = 0; r < 4; ++r) {
                float ss = 0.f;
                #pragma unroll
                for (int n = 0; n < 4; ++n) { float v = acc[m][n][r]; ss += v * v; }
                ss += __shfl_xor(ss, 1, 64);
                ss += __shfl_xor(ss, 2, 64);
                ss += __shfl_xor(ss, 4, 64);
                ss += __shfl_xor(ss, 8, 64);
                float sc = extra / (sqrtf(ss) + 1e-10f);
                const size_t rbase = (size_t)(rowb + m * 16 + r) * QKVW + colb0 + fr;
                #pragma unroll
                for (int n = 0; n < 4; ++n)
                    qkv[rbase + n * 16] = __float2bfloat16(acc[m][n][r] * sc);
            }
    } else {
        #pragma unroll
        for (int m = 0; m < 4; ++m) {
            const int row = rowb + m * 16;
            const int bb  = row >> 10;
            const int t0  = row & 1023;
            #pragma unroll
            for (int n = 0; n < 4; ++n) {
                const int cv = colb0 + fr + n * 16 - 1280;   // 0..255
                const int gg = cv >> 6, d = cv & 63;
                union { short4v s; __hip_bfloat16 h[4]; } u;
                u.h[0] = __float2bfloat16(acc[m][n][0]);
                u.h[1] = __float2bfloat16(acc[m][n][1]);
                u.h[2] = __float2bfloat16(acc[m][n][2]);
                u.h[3] = __float2bfloat16(acc[m][n][3]);
                *reinterpret_cast<short4v*>(
                    vt + ((size_t)((bb * G_ + gg) * HD_ + d)) * T_ + t0) = u.s;
            }
        }
    }
}

// ---------------------------------------------------------------------------
// Output projection GEMM: C = A * Bt^T -> fp32. (unchanged, verified)
// ---------------------------------------------------------------------------
__global__ __launch_bounds__(256) void gemm_tn_f32(
    const __hip_bfloat16* __restrict__ A,
    const __hip_bfloat16* __restrict__ Bt,
    float* __restrict__ C, int M, int N, int K)
{
    __shared__ __hip_bfloat16 As[2][128 * 32];
    __shared__ __hip_bfloat16 Bs[2][128 * 32];

    const int tid  = threadIdx.x;
    const int lane = tid & 63;
    const int wr   = (tid >> 6) >> 1;
    const int wc   = (tid >> 6) & 1;

    const int rpx = (M >> 7) >> 3;
    const int xcd = blockIdx.x & 7;
    const int lin = blockIdx.x >> 3;
    const int by  = xcd * rpx + (lin % rpx);
    const int bx  = lin / rpx;
    const int m0 = by * 128;
    const int n0 = bx * 128;

    f32x4 acc[4][4] = {};

    const int s0 = tid * 8,          sr0 = s0 >> 5, sc0 = s0 & 31;
    const int s1 = (256 + tid) * 8,  sr1 = s1 >> 5, sc1 = s1 & 31;

    const __hip_bfloat16* Ar0 = A  + (size_t)(m0 + sr0) * K + sc0;
    const __hip_bfloat16* Ar1 = A  + (size_t)(m0 + sr1) * K + sc1;
    const __hip_bfloat16* Br0 = Bt + (size_t)(n0 + sr0) * K + sc0;
    const __hip_bfloat16* Br1 = Bt + (size_t)(n0 + sr1) * K + sc1;

    const int fr = lane & 15;
    const int kf = (lane >> 4) * 8;

    GLOAD16(Ar0, &As[0][s0]);
    GLOAD16(Ar1, &As[0][s1]);
    GLOAD16(Br0, &Bs[0][s0]);
    GLOAD16(Br1, &Bs[0][s1]);
    __syncthreads();

    int cur = 0;
    for (int kk = 0; kk < K; kk += 32) {
        const int nxt = cur ^ 1;
        if (kk + 32 < K) {
            GLOAD16(Ar0 + kk + 32, &As[nxt][s0]);
            GLOAD16(Ar1 + kk + 32, &As[nxt][s1]);
            GLOAD16(Br0 + kk + 32, &Bs[nxt][s0]);
            GLOAD16(Br1 + kk + 32, &Bs[nxt][s1]);
        }
        short8 a[4], b[4];
        #pragma unroll
        for (int m = 0; m < 4; ++m)
            a[m] = *(const short8*)(&As[cur][(wr * 64 + m * 16 + fr) * 32 + kf]);
        #pragma unroll
        for (int n = 0; n < 4; ++n)
            b[n] = *(const short8*)(&Bs[cur][(wc * 64 + n * 16 + fr) * 32 + kf]);
        #pragma unroll
        for (int m = 0; m < 4; ++m)
            #pragma unroll
            for (int n = 0; n < 4; ++n)
                acc[m][n] = __builtin_amdgcn_mfma_f32_16x16x32_bf16(a[m], b[n], acc[m][n], 0, 0, 0);
        __syncthreads();
        cur = nxt;
    }

    const int rowb = m0 + wr * 64 + (lane >> 4) * 4;
    const int colb = n0 + wc * 64 + fr;
    #pragma unroll
    for (int m = 0; m < 4; ++m)
        #pragma unroll
        for (int n = 0; n < 4; ++n)
            #pragma unroll
            for (int r = 0; r < 4; ++r)
                C[(size_t)(rowb + m * 16 + r) * N + colb + n * 16] = acc[m][n][r];
}

// ---------------------------------------------------------------------------
// Flash attention, causal, GQA, MERGED paired q-tiles: one k-loop stages each
// tile once; qtB=15-pair computed every tile, qtA=pair when kt<=pair. Shared
// K/V fragment reads feed both chains (2x ILP). Degenerate softmax
// (p=exp2(s), scale folded into q). Dbuf staging, swizzled LDS, setprio.
// ---------------------------------------------------------------------------
__global__ __launch_bounds__(256) void attn_fwd(
    const __hip_bfloat16* __restrict__ qkv,
    const __hip_bfloat16* __restrict__ vt,
    __hip_bfloat16* __restrict__ out)   // [B,T,H*HD]
{
    const int pair = blockIdx.x;        // 0..7
    const int h  = blockIdx.y;
    const int b  = blockIdx.z;
    const int g  = h >> 2;

    const int tid  = threadIdx.x;
    const int lane = tid & 63;
    const int wid  = tid >> 6;

    __shared__ __hip_bfloat16 Ks[2 * 4096];
    __shared__ __hip_bfloat16 Vs[2 * 4096];
    __shared__ __hip_bfloat16 Ps[4 * 2 * 1024];   // 4 waves x 2 planes x 16x64

    const int fr  = lane & 15;
    const int kf  = (lane >> 4) * 8;
    const int kb  = kf * 2;
    const int swz = (fr & 7) << 4;

    const int srow = tid >> 3;                              // 0..31
    const int scol = ((tid & 7) * 8) ^ ((srow & 7) << 3);   // pre-swizzled col

    const size_t kgbase = (size_t)(b * T_) * QKVW + H_ * HD_ + g * HD_ + scol;
    const size_t vgbase = (size_t)((b * G_ + g) * HD_) * T_ + scol;

    char* PsB = (char*)Ps + wid * 4096;    // plane A at +0, plane B at +2048

    const int qtA = pair, qtB = 15 - pair;
    const int rbaseA = qtA * 64 + wid * 16 + (lane >> 4) * 4;
    const int rbaseB = qtB * 64 + wid * 16 + (lane >> 4) * 4;

    short8 qA0, qA1, qB0, qB1;
    {
        const size_t qa = ((size_t)(b * T_ + qtA * 64 + wid * 16 + fr)) * QKVW + h * HD_;
        const size_t qb = ((size_t)(b * T_ + qtB * 64 + wid * 16 + fr)) * QKVW + h * HD_;
        qA0 = *(const short8*)(qkv + qa + kf);
        qA1 = *(const short8*)(qkv + qa + 32 + kf);
        qB0 = *(const short8*)(qkv + qb + kf);
        qB1 = *(const short8*)(qkv + qb + 32 + kf);
    }

    float lsumA[4] = {0.f, 0.f, 0.f, 0.f}, lsumB[4] = {0.f, 0.f, 0.f, 0.f};
    f32x4 oA[4] = {}, oB[4] = {};

    // prologue: stage tile 0 into buf 0
    GLOAD16(qkv + kgbase + (size_t)srow * QKVW,        &Ks[tid * 8]);
    GLOAD16(qkv + kgbase + (size_t)(32 + srow) * QKVW, &Ks[2048 + tid * 8]);
    GLOAD16(vt + vgbase + (size_t)srow * T_,           &Vs[tid * 8]);
    GLOAD16(vt + vgbase + (size_t)(32 + srow) * T_,    &Vs[2048 + tid * 8]);
    __syncthreads();

    int cur = 0;
    for (int kt = 0; kt <= qtB; ++kt) {
        const bool doA = (kt <= qtA);
        const int nb = (cur ^ 1) * 4096;
        if (kt < qtB) {
            GLOAD16(qkv + kgbase + (size_t)((kt + 1) * 64 + srow) * QKVW,      &Ks[nb + tid * 8]);
            GLOAD16(qkv + kgbase + (size_t)((kt + 1) * 64 + 32 + srow) * QKVW, &Ks[nb + 2048 + tid * 8]);
            GLOAD16(vt + vgbase + (size_t)srow * T_ + (kt + 1) * 64,           &Vs[nb + tid * 8]);
            GLOAD16(vt + vgbase + (size_t)(32 + srow) * T_ + (kt + 1) * 64,    &Vs[nb + 2048 + tid * 8]);
        }

        char* KsB = (char*)(Ks + cur * 4096);
        char* VsB = (char*)(Vs + cur * 4096);

        // shared K fragments
        short8 bK0[4], bK1[4];
        #pragma unroll
        for (int nf = 0; nf < 4; ++nf) {
            const int row = fr + 16 * nf;
            bK0[nf] = *(const short8*)(KsB + row * 128 + (kb ^ swz));
            bK1[nf] = *(const short8*)(KsB + row * 128 + ((64 + kb) ^ swz));
        }

        f32x4 sA[4] = {}, sB[4] = {};
        __builtin_amdgcn_s_setprio(1);
        if (doA) {
            #pragma unroll
            for (int nf = 0; nf < 4; ++nf) {
                sA[nf] = __builtin_amdgcn_mfma_f32_16x16x32_bf16(qA0, bK0[nf], sA[nf], 0, 0, 0);
                sA[nf] = __builtin_amdgcn_mfma_f32_16x16x32_bf16(qA1, bK1[nf], sA[nf], 0, 0, 0);
            }
        }
        #pragma unroll
        for (int nf = 0; nf < 4; ++nf) {
            sB[nf] = __builtin_amdgcn_mfma_f32_16x16x32_bf16(qB0, bK0[nf], sB[nf], 0, 0, 0);
            sB[nf] = __builtin_amdgcn_mfma_f32_16x16x32_bf16(qB1, bK1[nf], sB[nf], 0, 0, 0);
        }
        __builtin_amdgcn_s_setprio(0);

        // exp + P writes (plane A / plane B)
        if (doA) {
            if (kt == qtA) {
                #pragma unroll
                for (int nf = 0; nf < 4; ++nf) {
                    int col = kt * 64 + fr + 16 * nf;
                    #pragma unroll
                    for (int r = 0; r < 4; ++r) {
                        float p = (col <= rbaseA + r) ? exp2_fast(sA[nf][r]) : 0.f;
                        lsumA[r] += p;
                        int q = (lane >> 4) * 4 + r;
                        *(__hip_bfloat16*)(PsB + q * 128 +
                            ((2 * (fr + 16 * nf)) ^ ((q & 7) << 4))) = __float2bfloat16(p);
                    }
                }
            } else {
                #pragma unroll
                for (int nf = 0; nf < 4; ++nf)
                    #pragma unroll
                    for (int r = 0; r < 4; ++r) {
                        float p = exp2_fast(sA[nf][r]);
                        lsumA[r] += p;
                        int q = (lane >> 4) * 4 + r;
                        *(__hip_bfloat16*)(PsB + q * 128 +
                            ((2 * (fr + 16 * nf)) ^ ((q & 7) << 4))) = __float2bfloat16(p);
                    }
            }
        }
        if (kt == qtB) {
            #pragma unroll
            for (int nf = 0; nf < 4; ++nf) {
                int col = kt * 64 + fr + 16 * nf;
                #pragma unroll
                for (int r = 0; r < 4; ++r) {
                    float p = (col <= rbaseB + r) ? exp2_fast(sB[nf][r]) : 0.f;
                    lsumB[r] += p;
                    int q = (lane >> 4) * 4 + r;
                    *(__hip_bfloat16*)(PsB + 2048 + q * 128 +
                        ((2 * (fr + 16 * nf)) ^ ((q & 7) << 4))) = __float2bfloat16(p);
                }
            }
        } else {
            #pragma unroll
            for (int nf = 0; nf < 4; ++nf)
                #pragma unroll
                for (int r = 0; r < 4; ++r) {
                    float p = exp2_fast(sB[nf][r]);
                    lsumB[r] += p;
                    int q = (lane >> 4) * 4 + r;
                    *(__hip_bfloat16*)(PsB + 2048 + q * 128 +
                        ((2 * (fr + 16 * nf)) ^ ((q & 7) << 4))) = __float2bfloat16(p);
                }
        }

        // shared V fragments + PV for both chains
        short8 bV0[4], bV1[4];
        #pragma unroll
        for (int nf = 0; nf < 4; ++nf) {
            const int row = fr + 16 * nf;
            bV0[nf] = *(const short8*)(VsB + row * 128 + (kb ^ swz));
            bV1[nf] = *(const short8*)(VsB + row * 128 + ((64 + kb) ^ swz));
        }
        __builtin_amdgcn_s_setprio(1);
        if (doA) {
            short8 pa0 = *(const short8*)(PsB + fr * 128 + (kb ^ swz));
            short8 pa1 = *(const short8*)(PsB + fr * 128 + ((64 + kb) ^ swz));
            #pragma unroll
            for (int nf = 0; nf < 4; ++nf) {
                oA[nf] = __builtin_amdgcn_mfma_f32_16x16x32_bf16(pa0, bV0[nf], oA[nf], 0, 0, 0);
                oA[nf] = __builtin_amdgcn_mfma_f32_16x16x32_bf16(pa1, bV1[nf], oA[nf], 0, 0, 0);
            }
        }
        {
            short8 pb0 = *(const short8*)(PsB + 2048 + fr * 128 + (kb ^ swz));
            short8 pb1 = *(const short8*)(PsB + 2048 + fr * 128 + ((64 + kb) ^ swz));
            #pragma unroll
            for (int nf = 0; nf < 4; ++nf) {
                oB[nf] = __builtin_amdgcn_mfma_f32_16x16x32_bf16(pb0, bV0[nf], oB[nf], 0, 0, 0);
                oB[nf] = __builtin_amdgcn_mfma_f32_16x16x32_bf16(pb1, bV1[nf], oB[nf], 0, 0, 0);
            }
        }
        __builtin_amdgcn_s_setprio(0);
        __syncthreads();   // drains next-tile vmcnt + protects K/V dbuf reuse
        cur ^= 1;
    }

    // epilogue: deferred row-sum reduce + normalize, both q-tiles
    float linvA[4], linvB[4];
    #pragma unroll
    for (int r = 0; r < 4; ++r) {
        float va = lsumA[r];
        va += __shfl_xor(va, 1, 64);
        va += __shfl_xor(va, 2, 64);
        va += __shfl_xor(va, 4, 64);
        va += __shfl_xor(va, 8, 64);
        linvA[r] = 1.0f / va;
        float vb = lsumB[r];
        vb += __shfl_xor(vb, 1, 64);
        vb += __shfl_xor(vb, 2, 64);
        vb += __shfl_xor(vb, 4, 64);
        vb += __shfl_xor(vb, 8, 64);
        linvB[r] = 1.0f / vb;
    }
    #pragma unroll
    for (int nf = 0; nf < 4; ++nf) {
        int col = fr + 16 * nf;
        #pragma unroll
        for (int r = 0; r < 4; ++r) {
            out[((size_t)(b * T_ + rbaseA + r)) * (H_ * HD_) + h * HD_ + col] =
                __float2bfloat16(oA[nf][r] * linvA[r]);
            out[((size_t)(b * T_ + rbaseB + r)) * (H_ * HD_) + h * HD_ + col] =
                __float2bfloat16(oB[nf][r] * linvB[r]);
        }
    }
}

extern "C" void kernel_launch(void* const* d_in, const int* in_sizes, int n_in,
                              void* d_out, int out_size, void* d_ws, size_t ws_size,
                              hipStream_t stream) {
    const float* x_f     = (const float*)d_in[0];   // [8192,1024]
    const float* w_qkv_f = (const float*)d_in[1];   // [1024,1536]
    const float* w_o_f   = (const float*)d_in[2];   // [1024,1024]
    float* out = (float*)d_out;

    const int NX  = B_ * T_ * D_;
    const int NWQ = D_ * QKVW;
    const int NWO = D_ * D_;

    __hip_bfloat16* attn_out = (__hip_bfloat16*)d_ws;              // [8192][1024]
    __hip_bfloat16* wqkvT = attn_out + NX;                         // [1536][1024]
    __hip_bfloat16* woT   = wqkvT + NWQ;                           // [1024][1024]
    __hip_bfloat16* qkv   = woT + NWO;                             // [8192][1536]
    __hip_bfloat16* vt    = qkv + (size_t)(B_ * T_) * QKVW;        // [B*G*64][1024]

    dim3 blk(256);

    cvt_transpose<<<dim3(QKVW / 32, D_ / 32), blk, 0, stream>>>(w_qkv_f, wqkvT, D_, QKVW);
    cvt_transpose<<<dim3(D_ / 32, D_ / 32), blk, 0, stream>>>(w_o_f, woT, D_, D_);

    // fused QKV GEMM (fp32 A, cvt fused) + L2-norm + scale-fold + V-transpose
    gemm_qkv<<<dim3((QKVW / 128) * ((B_ * T_) / 128)), blk, 0, stream>>>(
        x_f, wqkvT, qkv, vt);

    attn_fwd<<<dim3(8, H_, B_), blk, 0, stream>>>(qkv, vt, attn_out);

    // out = attn_out @ w_o  (grid 512, %8==0)
    gemm_tn_f32<<<dim3((D_ / 128) * ((B_ * T_) / 128)), blk, 0, stream>>>(
        attn_out, woT, out, B_ * T_, D_, D_);
}